// Round 8
// baseline (561.485 us; speedup 1.0000x reference)
//
#include <hip/hip_runtime.h>
#include <cstdint>
#include <cstddef>

typedef __attribute__((ext_vector_type(8))) short short8v;   // 8 bf16 = 4 VGPRs
typedef __attribute__((ext_vector_type(4))) short short4v;   // 4 bf16 = 8B
typedef __attribute__((ext_vector_type(4))) float f32x4;
typedef unsigned short ushort_t;

#define NBLK 512

__device__ inline unsigned short f2bf(float x) {
    unsigned int u = __float_as_uint(x);
    return (unsigned short)((u + 0x7FFFu + ((u >> 16) & 1u)) >> 16);   // RNE
}

// Grid-wide barrier: all NBLK blocks co-resident (guaranteed by
// __launch_bounds__(256,2): >=2 blocks/CU x 256 CU = 512). Counters zeroed
// by hipMemsetAsync before launch each call.
__device__ __forceinline__ void grid_barrier(int* __restrict__ bar, int idx) {
    __threadfence();
    __syncthreads();
    if (threadIdx.x == 0) {
        __hip_atomic_fetch_add(&bar[idx], 1, __ATOMIC_RELEASE, __HIP_MEMORY_SCOPE_AGENT);
        while (__hip_atomic_load(&bar[idx], __ATOMIC_ACQUIRE, __HIP_MEMORY_SCOPE_AGENT) < NBLK)
            __builtin_amdgcn_s_sleep(2);
    }
    __syncthreads();
    __threadfence();
}

// ---------------------------------------------------------------------------
// Mega kernel: 512 blocks x 256 threads, 5 phases, 4 grid barriers.
//  P1: pe-add (1024 tiles) + weight prep (64) + conv-weight pack (9)
//  P2: merged projection GEMM (768 tiles)
//  P3: conv as MFMA implicit GEMM (64 tiles)
//  P4: flash attention (512 tiles)
//  P5: output GEMM (256 tiles)
// LDS: manual union, max 34816 B (proj/out: As+Bs).
// ---------------------------------------------------------------------------
__global__ __launch_bounds__(256, 2) void mega_kernel(
    const float* __restrict__ src1, const float* __restrict__ src2,
    const float* __restrict__ Wq1, const float* __restrict__ Wq2,
    const float* __restrict__ Wk, const float* __restrict__ Wv,
    const float* __restrict__ Wo, const float* __restrict__ cw,
    const float* __restrict__ bq1, const float* __restrict__ bq2,
    const float* __restrict__ bk, const float* __restrict__ bv,
    const float* __restrict__ cb, const float* __restrict__ bo,
    ushort_t* __restrict__ X1, ushort_t* __restrict__ X2,
    ushort_t* __restrict__ WcatT, ushort_t* __restrict__ WoT,
    float* __restrict__ bcat, ushort_t* __restrict__ Wcv2,
    ushort_t* __restrict__ Qbf, ushort_t* __restrict__ Kbf,
    ushort_t* __restrict__ VTbf, ushort_t* __restrict__ CVbf,
    ushort_t* __restrict__ AObf, float* __restrict__ out,
    int* __restrict__ bar)
{
    __shared__ ushort_t SMEM[17408];    // 34816 B
    int bid = blockIdx.x;
    int t = threadIdx.x;

    // ======================= Phase 1: pe + weight prep =======================
    {
        ushort_t (*Ts)[72] = (ushort_t(*)[72])SMEM;
        for (int vt = bid; vt < 1097; vt += NBLK) {
            if (vt < 1024) {
                int n = vt, c = t;
                int row = n >> 5, col = n & 31;
                float pos = (c < 128) ? (float)(row + 1) : (float)(col + 1);
                float freq = expf(-0.14391156831212787f * (float)(c & 63));
                float pe = sinf(pos * freq);
                for (int b = 0; b < 4; ++b) {
                    size_t idx = ((size_t)b * 1024 + n) * 256 + c;
                    X1[idx] = f2bf(src1[idx] + pe);
                    X2[idx] = f2bf(src2[idx] + pe);
                }
            } else if (vt < 1088) {
                int idx = vt - 1024;
                int kt = idx & 3, ct = idx >> 2;
                int k0 = kt * 64;
                const float* W; int csrc; int fold = 0; ushort_t* dst; int dstbase;
                if (ct < 2)       { W = Wq1; csrc = ct * 64;        fold = 1; dst = WcatT; dstbase = ct * 64; }
                else if (ct < 4)  { W = Wq2; csrc = (ct - 2) * 64;  fold = 1; dst = WcatT; dstbase = ct * 64; }
                else if (ct < 8)  { W = Wk;  csrc = (ct - 4) * 64;            dst = WcatT; dstbase = ct * 64; }
                else if (ct < 12) { W = Wv;  csrc = (ct - 8) * 64;            dst = WcatT; dstbase = ct * 64; }
                else              { W = Wo;  csrc = (ct - 12) * 64;           dst = WoT;   dstbase = (ct - 12) * 64; }
                if (kt == 0) {
                    if (ct == 0 && t < 128) bcat[t] = bq1[t] + bq1[t + 128];
                    if (ct == 2 && t < 128) bcat[128 + t] = bq2[t] + bq2[t + 128];
                    if (ct == 4) bcat[256 + t] = bk[t];
                    if (ct == 8) bcat[512 + t] = bv[t];
                }
                int kr = t >> 2, cq = t & 3;
                #pragma unroll
                for (int i = 0; i < 4; ++i) {
                    int cc = cq * 16 + i * 4;
                    float4 v = *(const float4*)&W[(size_t)(k0 + kr) * 256 + csrc + cc];
                    if (fold) {
                        float4 v2 = *(const float4*)&W[(size_t)(k0 + kr) * 256 + csrc + cc + 128];
                        v.x += v2.x; v.y += v2.y; v.z += v2.z; v.w += v2.w;
                    }
                    Ts[kr][cc + 0] = f2bf(v.x); Ts[kr][cc + 1] = f2bf(v.y);
                    Ts[kr][cc + 2] = f2bf(v.z); Ts[kr][cc + 3] = f2bf(v.w);
                }
                __syncthreads();
                int cr = t >> 2, kq = t & 3;
                ushort_t tmp[16];
                #pragma unroll
                for (int i = 0; i < 16; ++i) tmp[i] = Ts[kq * 16 + i][cr];
                *(short8v*)&dst[(size_t)(dstbase + cr) * 256 + k0 + kq * 16]     = *(short8v*)&tmp[0];
                *(short8v*)&dst[(size_t)(dstbase + cr) * 256 + k0 + kq * 16 + 8] = *(short8v*)&tmp[8];
            } else {
                int tap = vt - 1088;
                int ci = t >> 2, co0 = (t & 3) * 16;
                #pragma unroll
                for (int i = 0; i < 16; ++i)
                    Ts[ci][co0 + i] = f2bf(cw[((size_t)(tap * 64 + ci)) * 64 + co0 + i]);
                __syncthreads();
                int co = t >> 2, ci0 = (t & 3) * 16;
                ushort_t tmp[16];
                #pragma unroll
                for (int i = 0; i < 16; ++i) tmp[i] = Ts[ci0 + i][co];
                int kh = ci0 >> 5;
                int f = (tap * 2 + kh) * 4 + (co >> 4);
                int off = f * 512 + (co & 15) * 32 + (ci0 & 31);
                *(short8v*)&Wcv2[off]     = *(short8v*)&tmp[0];
                *(short8v*)&Wcv2[off + 8] = *(short8v*)&tmp[8];
            }
            __syncthreads();   // Ts reuse across grid-stride iterations
        }
    }
    grid_barrier(bar, 0);

    // ======================= Phase 2: projection GEMM ========================
    {
        ushort_t (*As)[136] = (ushort_t(*)[136])SMEM;
        ushort_t (*Bs)[136] = (ushort_t(*)[136])(SMEM + 8704);
        int w = t >> 6, l = t & 63, lr = l & 15, g = l >> 4;
        int wr = w >> 1, wc = w & 1;
        int tr = t >> 2, tq = t & 3;

        for (int vt = bid; vt < 768; vt += NBLK) {
            int colBase = (vt % 12) * 64, rowBase = (vt / 12) * 64;
            const ushort_t* A = (colBase >= 128 && colBase < 256) ? X2 : X1;
            f32x4 acc[2][2] = {};

            for (int kb = 0; kb < 256; kb += 128) {
                #pragma unroll
                for (int i = 0; i < 4; ++i)
                    *(short8v*)&As[tr][tq * 32 + i * 8] =
                        *(const short8v*)&A[(size_t)(rowBase + tr) * 256 + kb + tq * 32 + i * 8];
                #pragma unroll
                for (int i = 0; i < 4; ++i)
                    *(short8v*)&Bs[tr][tq * 32 + i * 8] =
                        *(const short8v*)&WcatT[(size_t)(colBase + tr) * 256 + kb + tq * 32 + i * 8];
                __syncthreads();
                #pragma unroll
                for (int ks = 0; ks < 4; ++ks) {
                    short8v a0 = *(const short8v*)&As[wr * 32 + lr][ks * 32 + g * 8];
                    short8v a1 = *(const short8v*)&As[wr * 32 + 16 + lr][ks * 32 + g * 8];
                    short8v b0 = *(const short8v*)&Bs[wc * 32 + lr][ks * 32 + g * 8];
                    short8v b1 = *(const short8v*)&Bs[wc * 32 + 16 + lr][ks * 32 + g * 8];
                    acc[0][0] = __builtin_amdgcn_mfma_f32_16x16x32_bf16(a0, b0, acc[0][0], 0, 0, 0);
                    acc[0][1] = __builtin_amdgcn_mfma_f32_16x16x32_bf16(a0, b1, acc[0][1], 0, 0, 0);
                    acc[1][0] = __builtin_amdgcn_mfma_f32_16x16x32_bf16(a1, b0, acc[1][0], 0, 0, 0);
                    acc[1][1] = __builtin_amdgcn_mfma_f32_16x16x32_bf16(a1, b1, acc[1][1], 0, 0, 0);
                }
                __syncthreads();
            }

            const float scale = 0.25503532182457352f;   // log2(e)/sqrt(32)
            #pragma unroll
            for (int fr = 0; fr < 2; ++fr)
                #pragma unroll
                for (int fc = 0; fc < 2; ++fc) {
                    int c = colBase + wc * 32 + fc * 16 + lr;
                    float bv = bcat[c];
                    int nb = rowBase + wr * 32 + fr * 16 + g * 4;
                    int b = nb >> 10;
                    if (c < 512) {
                        #pragma unroll
                        for (int r = 0; r < 4; ++r) {
                            int n = nb + r;
                            float v = acc[fr][fc][r] + bv;
                            if (c < 128) {
                                int h = 4 + (c >> 5), d = c & 31;
                                Qbf[(((size_t)(b * 8 + h) << 10) | (n & 1023)) * 32 + d] = f2bf(v * scale);
                            } else if (c < 256) {
                                int c2 = c - 128;
                                int h = c2 >> 5, d = c2 & 31;
                                Qbf[(((size_t)(b * 8 + h) << 10) | (n & 1023)) * 32 + d] = f2bf(v * scale);
                            } else {
                                int c3 = c - 256;
                                if (c3 < 128) {
                                    int h = 4 + (c3 >> 5), d = c3 & 31;
                                    Kbf[(((size_t)(b * 8 + h) << 10) | (n & 1023)) * 32 + d] = f2bf(v);
                                } else if (c3 < 192) {
                                    CVbf[(size_t)n * 64 + (c3 - 128)] = f2bf(v);
                                } else {
                                    int h = 2 + ((c3 - 192) >> 5), d = c3 & 31;
                                    Kbf[(((size_t)(b * 8 + h) << 10) | (n & 1023)) * 32 + d] = f2bf(v);
                                }
                            }
                        }
                    } else {
                        int c4 = c - 512;
                        int h = c4 >> 5, d = c4 & 31;
                        short4v pk;
                        #pragma unroll
                        for (int r = 0; r < 4; ++r) pk[r] = (short)f2bf(acc[fr][fc][r] + bv);
                        *(short4v*)&VTbf[((size_t)((b * 8 + h) * 32 + d)) * 1024 + (nb & 1023)] = pk;
                    }
                }
            __syncthreads();
        }
    }
    grid_barrier(bar, 1);

    // ======================= Phase 3: conv MFMA ==============================
    if (bid < 64) {
        ushort_t* Xs = SMEM;               // 8704 ushorts
        int b = bid >> 4, y0 = (bid & 15) * 2;
        int w = t >> 6, l = t & 63, lr = l & 15, g = l >> 4;

        for (int p = t >> 1; p < 136; p += 128) {
            int ry = p / 34, xc = p % 34;
            int ci0 = (t & 1) * 32;
            int gy = y0 - 1 + ry, gx = xc - 1;
            int base = p << 6;
            int sw = (xc & 7) << 3;
            if ((unsigned)gy < 32u && (unsigned)gx < 32u) {
                const ushort_t* src = &CVbf[((size_t)(b * 1024 + gy * 32 + gx)) * 64 + ci0];
                #pragma unroll
                for (int k = 0; k < 4; ++k)
                    *(short8v*)&Xs[(base + ci0 + k * 8) ^ sw] = *(const short8v*)&src[k * 8];
            } else {
                short8v z = {};
                #pragma unroll
                for (int k = 0; k < 4; ++k)
                    *(short8v*)&Xs[(base + ci0 + k * 8) ^ sw] = z;
            }
        }
        __syncthreads();

        int yl = w >> 1, xb = (w & 1) * 16;
        f32x4 acc[4] = {};
        #pragma unroll
        for (int ky = 0; ky < 3; ++ky)
            #pragma unroll
            for (int kx = 0; kx < 3; ++kx) {
                int tap = ky * 3 + kx;
                #pragma unroll
                for (int kh = 0; kh < 2; ++kh) {
                    int xa = xb + lr + kx;
                    int e = (((yl + ky) * 34 + xa) << 6) + kh * 32 + g * 8;
                    short8v af = *(const short8v*)&Xs[e ^ ((xa & 7) << 3)];
                    int fb = (tap * 2 + kh) * 4 * 512 + lr * 32 + g * 8;
                    #pragma unroll
                    for (int nf = 0; nf < 4; ++nf) {
                        short8v bf_ = *(const short8v*)&Wcv2[fb + nf * 512];
                        acc[nf] = __builtin_amdgcn_mfma_f32_16x16x32_bf16(af, bf_, acc[nf], 0, 0, 0);
                    }
                }
            }

        #pragma unroll
        for (int nf = 0; nf < 4; ++nf) {
            int co = nf * 16 + lr;
            float bias = cb[co];
            int h = co >> 5, d = co & 31;
            #pragma unroll
            for (int r = 0; r < 4; ++r) {
                int px = w * 16 + g * 4 + r;
                int n = y0 * 32 + px;
                Kbf[(((size_t)(b * 8 + h) << 10) | n) * 32 + d] = f2bf(acc[nf][r] + bias);
            }
        }
    }
    grid_barrier(bar, 2);

    // ======================= Phase 4: flash attention ========================
    {
        ushort_t (*Kt)[64][32] = (ushort_t(*)[64][32])SMEM;          // [2][64][32]
        ushort_t (*VT)[32][72] = (ushort_t(*)[32][72])(SMEM + 4096); // [2][32][72]
        ushort_t (*Ps)[16][72] = (ushort_t(*)[16][72])(SMEM + 8704); // [4][16][72]

        int bh = bid >> 4, q0 = (bid & 15) * 64;
        int w = t >> 6, l = t & 63, lr = l & 15, g = l >> 4;
        int vd = t >> 3, vn = (t & 7) * 8;

        short8v qfrag = *(const short8v*)&Qbf[((size_t)bh * 1024 + q0 + w * 16 + lr) * 32 + g * 8];

        f32x4 accO[2] = {};
        float lsum = 0.f;
        const f32x4 zero = {};

        ((short8v*)&Kt[0][0][0])[t] =
            *(const short8v*)&Kbf[((size_t)bh * 1024) * 32 + t * 8];
        *(short8v*)&VT[0][vd][vn] =
            *(const short8v*)&VTbf[((size_t)bh * 32 + vd) * 1024 + vn];

        for (int mt = 0; mt < 16; ++mt) {
            int cur = mt & 1, nb = cur ^ 1;
            __syncthreads();

            short8v kreg, vreg;
            bool hasNext = (mt + 1) < 16;
            if (hasNext) {
                int m1 = (mt + 1) * 64;
                kreg = *(const short8v*)&Kbf[((size_t)bh * 1024 + m1) * 32 + t * 8];
                vreg = *(const short8v*)&VTbf[((size_t)bh * 32 + vd) * 1024 + m1 + vn];
            }

            f32x4 st[4];
            #pragma unroll
            for (int tt = 0; tt < 4; ++tt) {
                short8v kf = *(const short8v*)&Kt[cur][tt * 16 + lr][g * 8];
                st[tt] = __builtin_amdgcn_mfma_f32_16x16x32_bf16(kf, qfrag, zero, 0, 0, 0);
            }

            #pragma unroll
            for (int tt = 0; tt < 4; ++tt) {
                float p0 = exp2f(st[tt][0]), p1 = exp2f(st[tt][1]);
                float p2 = exp2f(st[tt][2]), p3 = exp2f(st[tt][3]);
                lsum += (p0 + p1) + (p2 + p3);
                short4v pw;
                pw[0] = (short)f2bf(p0); pw[1] = (short)f2bf(p1);
                pw[2] = (short)f2bf(p2); pw[3] = (short)f2bf(p3);
                *(short4v*)&Ps[w][lr][tt * 16 + g * 4] = pw;
            }

            #pragma unroll
            for (int kt = 0; kt < 2; ++kt) {
                short8v pa = *(const short8v*)&Ps[w][lr][kt * 32 + g * 8];
                #pragma unroll
                for (int nt = 0; nt < 2; ++nt) {
                    short8v vb = *(const short8v*)&VT[cur][nt * 16 + lr][kt * 32 + g * 8];
                    accO[nt] = __builtin_amdgcn_mfma_f32_16x16x32_bf16(pa, vb, accO[nt], 0, 0, 0);
                }
            }

            if (hasNext) {
                ((short8v*)&Kt[nb][0][0])[t] = kreg;
                *(short8v*)&VT[nb][vd][vn] = vreg;
            }
        }

        lsum += __shfl_xor(lsum, 16);
        lsum += __shfl_xor(lsum, 32);

        int b = bh >> 3, h = bh & 7;
        #pragma unroll
        for (int r = 0; r < 4; ++r) {
            float lv = __uint_as_float((unsigned)__builtin_amdgcn_ds_bpermute(
                (g * 4 + r) * 4, (int)__float_as_uint(lsum)));
            float inv = 1.0f / lv;
            int n = q0 + w * 16 + g * 4 + r;
            #pragma unroll
            for (int nt = 0; nt < 2; ++nt)
                AObf[((size_t)(b * 1024 + n)) * 256 + h * 32 + nt * 16 + lr] =
                    f2bf(accO[nt][r] * inv);
        }
    }
    grid_barrier(bar, 3);

    // ======================= Phase 5: output GEMM ============================
    if (bid < 256) {
        ushort_t (*As)[136] = (ushort_t(*)[136])SMEM;
        ushort_t (*Bs)[136] = (ushort_t(*)[136])(SMEM + 8704);
        int colBase = (bid & 3) * 64, rowBase = (bid >> 2) * 64;
        int w = t >> 6, l = t & 63, lr = l & 15, g = l >> 4;
        int wr = w >> 1, wc = w & 1;
        int tr = t >> 2, tq = t & 3;
        f32x4 acc[2][2] = {};

        for (int kb = 0; kb < 256; kb += 128) {
            #pragma unroll
            for (int i = 0; i < 4; ++i)
                *(short8v*)&As[tr][tq * 32 + i * 8] =
                    *(const short8v*)&AObf[(size_t)(rowBase + tr) * 256 + kb + tq * 32 + i * 8];
            #pragma unroll
            for (int i = 0; i < 4; ++i)
                *(short8v*)&Bs[tr][tq * 32 + i * 8] =
                    *(const short8v*)&WoT[(size_t)(colBase + tr) * 256 + kb + tq * 32 + i * 8];
            __syncthreads();
            #pragma unroll
            for (int ks = 0; ks < 4; ++ks) {
                short8v a0 = *(const short8v*)&As[wr * 32 + lr][ks * 32 + g * 8];
                short8v a1 = *(const short8v*)&As[wr * 32 + 16 + lr][ks * 32 + g * 8];
                short8v b0 = *(const short8v*)&Bs[wc * 32 + lr][ks * 32 + g * 8];
                short8v b1 = *(const short8v*)&Bs[wc * 32 + 16 + lr][ks * 32 + g * 8];
                acc[0][0] = __builtin_amdgcn_mfma_f32_16x16x32_bf16(a0, b0, acc[0][0], 0, 0, 0);
                acc[0][1] = __builtin_amdgcn_mfma_f32_16x16x32_bf16(a0, b1, acc[0][1], 0, 0, 0);
                acc[1][0] = __builtin_amdgcn_mfma_f32_16x16x32_bf16(a1, b0, acc[1][0], 0, 0, 0);
                acc[1][1] = __builtin_amdgcn_mfma_f32_16x16x32_bf16(a1, b1, acc[1][1], 0, 0, 0);
            }
            __syncthreads();
        }

        #pragma unroll
        for (int fr = 0; fr < 2; ++fr)
            #pragma unroll
            for (int fc = 0; fc < 2; ++fc) {
                int c = colBase + wc * 32 + fc * 16 + lr;
                float bv = bo[c];
                int nb = rowBase + wr * 32 + fr * 16 + g * 4;
                #pragma unroll
                for (int r = 0; r < 4; ++r)
                    out[(size_t)(nb + r) * 256 + c] = acc[fr][fc][r] + bv;
            }
    }
}

// ---------------------------------------------------------------------------
extern "C" void kernel_launch(void* const* d_in, const int* in_sizes, int n_in,
                              void* d_out, int out_size, void* d_ws, size_t ws_size,
                              hipStream_t stream)
{
    const float* src1 = (const float*)d_in[0];
    const float* src2 = (const float*)d_in[1];
    const float* Wq1  = (const float*)d_in[2];
    const float* bq1  = (const float*)d_in[3];
    const float* Wq2  = (const float*)d_in[4];
    const float* bq2  = (const float*)d_in[5];
    const float* Wk   = (const float*)d_in[6];
    const float* bk   = (const float*)d_in[7];
    const float* Wv   = (const float*)d_in[8];
    const float* bv   = (const float*)d_in[9];
    const float* cw   = (const float*)d_in[10];
    const float* cb   = (const float*)d_in[11];
    const float* Wo   = (const float*)d_in[12];
    const float* bo   = (const float*)d_in[13];
    float* out = (float*)d_out;

    char* base = (char*)d_ws;
    const size_t MB = 1u << 20;
    const size_t KB = 1u << 10;
    ushort_t* X1bf = (ushort_t*)(base + 0 * MB);     // 2 MB
    ushort_t* X2bf = (ushort_t*)(base + 2 * MB);     // 2 MB
    ushort_t* Qbf  = (ushort_t*)(base + 4 * MB);     // 2 MB  [32 bh][1024][32]
    ushort_t* Kbf  = (ushort_t*)(base + 6 * MB);     // 2 MB
    ushort_t* VTbf = (ushort_t*)(base + 8 * MB);     // 2 MB  [32 bh][32][1024]
    ushort_t* AObf = (ushort_t*)(base + 10 * MB);    // 2 MB  [4096][256]
    ushort_t* CVbf = (ushort_t*)(base + 12 * MB);    // 512 KB [4096][64]
    ushort_t* WcatT= (ushort_t*)(base + 12 * MB + 512 * KB);   // 384 KB
    ushort_t* WoT  = (ushort_t*)(base + 12 * MB + 896 * KB);   // 128 KB
    float*    bcat = (float*)(base + 13 * MB);                 // 3 KB
    ushort_t* Wcv2 = (ushort_t*)(base + 13 * MB + 4 * KB);     // 72 KB
    int*      bar  = (int*)(base + 14 * MB);                   // 16 B

    hipMemsetAsync(bar, 0, 4 * sizeof(int), stream);
    mega_kernel<<<NBLK, 256, 0, stream>>>(
        src1, src2, Wq1, Wq2, Wk, Wv, Wo, cw, bq1, bq2, bk, bv, cb, bo,
        X1bf, X2bf, WcatT, WoT, bcat, Wcv2, Qbf, Kbf, VTbf, CVbf, AObf, out, bar);
}

// Round 9
// 61.939 us; speedup vs baseline: 9.0651x; 9.0651x over previous
//
#include <hip/hip_runtime.h>
#include <cstdint>
#include <cstddef>

typedef __attribute__((ext_vector_type(8))) short short8v;   // 8 bf16 = 4 VGPRs
typedef __attribute__((ext_vector_type(4))) short short4v;   // 4 bf16 = 8B
typedef __attribute__((ext_vector_type(4))) float f32x4;
typedef unsigned short ushort_t;

__device__ inline unsigned short f2bf(float x) {
    unsigned int u = __float_as_uint(x);
    return (unsigned short)((u + 0x7FFFu + ((u >> 16) & 1u)) >> 16);   // RNE
}

// ---------------------------------------------------------------------------
// Kernel 1 (fused): blocks [0,1024): X1/X2 = bf16(src + pe)
//                   blocks [1024,1088): QKVO weight transpose/fold prep
//                   blocks [1088,1097): conv weight pack (per tap)
// ---------------------------------------------------------------------------
__global__ __launch_bounds__(256) void pe_prep_kernel(
    const float* __restrict__ src1, const float* __restrict__ src2,
    const float* __restrict__ Wq1, const float* __restrict__ Wq2,
    const float* __restrict__ Wk, const float* __restrict__ Wv,
    const float* __restrict__ Wo, const float* __restrict__ cw,
    const float* __restrict__ bq1, const float* __restrict__ bq2,
    const float* __restrict__ bk, const float* __restrict__ bv,
    ushort_t* __restrict__ X1, ushort_t* __restrict__ X2,
    ushort_t* __restrict__ WcatT, ushort_t* __restrict__ WoT,
    float* __restrict__ bcat, ushort_t* __restrict__ Wcv2)
{
    __shared__ ushort_t Ts[64][72];
    int bx = blockIdx.x;
    int t = threadIdx.x;

    if (bx < 1024) {
        int n = bx, c = t;
        int row = n >> 5, col = n & 31;
        float pos = (c < 128) ? (float)(row + 1) : (float)(col + 1);
        float freq = expf(-0.14391156831212787f * (float)(c & 63));
        float pe = sinf(pos * freq);
        for (int b = 0; b < 4; ++b) {
            size_t idx = ((size_t)b * 1024 + n) * 256 + c;
            X1[idx] = f2bf(src1[idx] + pe);
            X2[idx] = f2bf(src2[idx] + pe);
        }
        return;
    }

    if (bx < 1088) {
        int idx = bx - 1024;
        int kt = idx & 3, ct = idx >> 2;
        int k0 = kt * 64;
        const float* W; int csrc; int fold = 0; ushort_t* dst; int dstbase;
        if (ct < 2)       { W = Wq1; csrc = ct * 64;        fold = 1; dst = WcatT; dstbase = ct * 64; }
        else if (ct < 4)  { W = Wq2; csrc = (ct - 2) * 64;  fold = 1; dst = WcatT; dstbase = ct * 64; }
        else if (ct < 8)  { W = Wk;  csrc = (ct - 4) * 64;            dst = WcatT; dstbase = ct * 64; }
        else if (ct < 12) { W = Wv;  csrc = (ct - 8) * 64;            dst = WcatT; dstbase = ct * 64; }
        else              { W = Wo;  csrc = (ct - 12) * 64;           dst = WoT;   dstbase = (ct - 12) * 64; }
        if (kt == 0) {
            if (ct == 0 && t < 128) bcat[t] = bq1[t] + bq1[t + 128];
            if (ct == 2 && t < 128) bcat[128 + t] = bq2[t] + bq2[t + 128];
            if (ct == 4) bcat[256 + t] = bk[t];
            if (ct == 8) bcat[512 + t] = bv[t];
        }

        int kr = t >> 2, cq = t & 3;
        #pragma unroll
        for (int i = 0; i < 4; ++i) {
            int cc = cq * 16 + i * 4;
            float4 v = *(const float4*)&W[(size_t)(k0 + kr) * 256 + csrc + cc];
            if (fold) {
                float4 v2 = *(const float4*)&W[(size_t)(k0 + kr) * 256 + csrc + cc + 128];
                v.x += v2.x; v.y += v2.y; v.z += v2.z; v.w += v2.w;
            }
            Ts[kr][cc + 0] = f2bf(v.x); Ts[kr][cc + 1] = f2bf(v.y);
            Ts[kr][cc + 2] = f2bf(v.z); Ts[kr][cc + 3] = f2bf(v.w);
        }
        __syncthreads();
        int cr = t >> 2, kq = t & 3;
        ushort_t tmp[16];
        #pragma unroll
        for (int i = 0; i < 16; ++i) tmp[i] = Ts[kq * 16 + i][cr];
        *(short8v*)&dst[(size_t)(dstbase + cr) * 256 + k0 + kq * 16]     = *(short8v*)&tmp[0];
        *(short8v*)&dst[(size_t)(dstbase + cr) * 256 + k0 + kq * 16 + 8] = *(short8v*)&tmp[8];
        return;
    }

    {
        int tap = bx - 1088;
        int ci = t >> 2, co0 = (t & 3) * 16;
        #pragma unroll
        for (int i = 0; i < 16; ++i)
            Ts[ci][co0 + i] = f2bf(cw[((size_t)(tap * 64 + ci)) * 64 + co0 + i]);
        __syncthreads();
        int co = t >> 2, ci0 = (t & 3) * 16;
        ushort_t tmp[16];
        #pragma unroll
        for (int i = 0; i < 16; ++i) tmp[i] = Ts[ci0 + i][co];
        int kh = ci0 >> 5;
        int f = (tap * 2 + kh) * 4 + (co >> 4);
        int off = f * 512 + (co & 15) * 32 + (ci0 & 31);
        *(short8v*)&Wcv2[off]     = *(short8v*)&tmp[0];
        *(short8v*)&Wcv2[off + 8] = *(short8v*)&tmp[8];
    }
}

// ---------------------------------------------------------------------------
// Kernel 2: merged projection GEMM, LDS-FREE (all operands L2-resident;
// fragments loaded directly as 16B global reads; zero barriers).
// grid (12, 64); 64x64 tile, 4 waves (2x2 of 32x32 each).
// ---------------------------------------------------------------------------
__global__ __launch_bounds__(256) void proj_gemm(
    const ushort_t* __restrict__ X1, const ushort_t* __restrict__ X2,
    const ushort_t* __restrict__ WcatT, const float* __restrict__ bcat,
    ushort_t* __restrict__ Qbf, ushort_t* __restrict__ Kbf,
    ushort_t* __restrict__ VTbf, ushort_t* __restrict__ CVbf)
{
    int colBase = blockIdx.x * 64, rowBase = blockIdx.y * 64;
    const ushort_t* A = (colBase >= 128 && colBase < 256) ? X2 : X1;
    int tid = threadIdx.x;
    int w = tid >> 6, l = tid & 63, lr = l & 15, g = l >> 4;
    int wr = w >> 1, wc = w & 1;
    f32x4 acc[2][2] = {};

    const ushort_t* Ar0 = A + (size_t)(rowBase + wr * 32 + lr) * 256 + g * 8;
    const ushort_t* Ar1 = Ar0 + 16 * 256;
    const ushort_t* Br0 = WcatT + (size_t)(colBase + wc * 32 + lr) * 256 + g * 8;
    const ushort_t* Br1 = Br0 + 16 * 256;

    #pragma unroll
    for (int k = 0; k < 8; ++k) {
        int kk = k * 32;
        short8v a0 = *(const short8v*)&Ar0[kk];
        short8v a1 = *(const short8v*)&Ar1[kk];
        short8v b0 = *(const short8v*)&Br0[kk];
        short8v b1 = *(const short8v*)&Br1[kk];
        acc[0][0] = __builtin_amdgcn_mfma_f32_16x16x32_bf16(a0, b0, acc[0][0], 0, 0, 0);
        acc[0][1] = __builtin_amdgcn_mfma_f32_16x16x32_bf16(a0, b1, acc[0][1], 0, 0, 0);
        acc[1][0] = __builtin_amdgcn_mfma_f32_16x16x32_bf16(a1, b0, acc[1][0], 0, 0, 0);
        acc[1][1] = __builtin_amdgcn_mfma_f32_16x16x32_bf16(a1, b1, acc[1][1], 0, 0, 0);
    }

    const float scale = 0.25503532182457352f;   // log2(e)/sqrt(32)
    #pragma unroll
    for (int fr = 0; fr < 2; ++fr)
        #pragma unroll
        for (int fc = 0; fc < 2; ++fc) {
            int c = colBase + wc * 32 + fc * 16 + lr;
            float bv = bcat[c];
            int nb = rowBase + wr * 32 + fr * 16 + g * 4;
            int b = nb >> 10;
            if (c < 512) {
                #pragma unroll
                for (int r = 0; r < 4; ++r) {
                    int n = nb + r;
                    float v = acc[fr][fc][r] + bv;
                    if (c < 128) {
                        int h = 4 + (c >> 5), d = c & 31;
                        Qbf[(((size_t)(b * 8 + h) << 10) | (n & 1023)) * 32 + d] = f2bf(v * scale);
                    } else if (c < 256) {
                        int c2 = c - 128;
                        int h = c2 >> 5, d = c2 & 31;
                        Qbf[(((size_t)(b * 8 + h) << 10) | (n & 1023)) * 32 + d] = f2bf(v * scale);
                    } else {
                        int c3 = c - 256;
                        if (c3 < 128) {
                            int h = 4 + (c3 >> 5), d = c3 & 31;
                            Kbf[(((size_t)(b * 8 + h) << 10) | (n & 1023)) * 32 + d] = f2bf(v);
                        } else if (c3 < 192) {
                            CVbf[(size_t)n * 64 + (c3 - 128)] = f2bf(v);
                        } else {
                            int h = 2 + ((c3 - 192) >> 5), d = c3 & 31;
                            Kbf[(((size_t)(b * 8 + h) << 10) | (n & 1023)) * 32 + d] = f2bf(v);
                        }
                    }
                }
            } else {
                int c4 = c - 512;
                int h = c4 >> 5, d = c4 & 31;
                short4v pk;
                #pragma unroll
                for (int r = 0; r < 4; ++r) pk[r] = (short)f2bf(acc[fr][fc][r] + bv);
                *(short4v*)&VTbf[((size_t)((b * 8 + h) * 32 + d)) * 1024 + (nb & 1023)] = pk;
            }
        }
}

// ---------------------------------------------------------------------------
// Kernel 3: 3x3 SAME conv as MFMA implicit GEMM (64 blocks). (unchanged)
// ---------------------------------------------------------------------------
__global__ __launch_bounds__(256) void conv_mfma(
    const ushort_t* __restrict__ CVbf, const ushort_t* __restrict__ Wcv2,
    const float* __restrict__ cb, ushort_t* __restrict__ Kbf)
{
    __shared__ ushort_t Xs[8704];          // 4*34*64
    int blk = blockIdx.x;
    int b = blk >> 4, y0 = (blk & 15) * 2;
    int tid = threadIdx.x, w = tid >> 6, l = tid & 63, lr = l & 15, g = l >> 4;

    for (int p = tid >> 1; p < 136; p += 128) {
        int ry = p / 34, xc = p % 34;
        int ci0 = (tid & 1) * 32;
        int gy = y0 - 1 + ry, gx = xc - 1;
        int base = p << 6;
        int sw = (xc & 7) << 3;
        if ((unsigned)gy < 32u && (unsigned)gx < 32u) {
            const ushort_t* src = &CVbf[((size_t)(b * 1024 + gy * 32 + gx)) * 64 + ci0];
            #pragma unroll
            for (int k = 0; k < 4; ++k)
                *(short8v*)&Xs[(base + ci0 + k * 8) ^ sw] = *(const short8v*)&src[k * 8];
        } else {
            short8v z = {};
            #pragma unroll
            for (int k = 0; k < 4; ++k)
                *(short8v*)&Xs[(base + ci0 + k * 8) ^ sw] = z;
        }
    }
    __syncthreads();

    int yl = w >> 1, xb = (w & 1) * 16;
    f32x4 acc[4] = {};
    #pragma unroll
    for (int ky = 0; ky < 3; ++ky)
        #pragma unroll
        for (int kx = 0; kx < 3; ++kx) {
            int tap = ky * 3 + kx;
            #pragma unroll
            for (int kh = 0; kh < 2; ++kh) {
                int xa = xb + lr + kx;
                int e = (((yl + ky) * 34 + xa) << 6) + kh * 32 + g * 8;
                short8v af = *(const short8v*)&Xs[e ^ ((xa & 7) << 3)];
                int fb = (tap * 2 + kh) * 4 * 512 + lr * 32 + g * 8;
                #pragma unroll
                for (int nf = 0; nf < 4; ++nf) {
                    short8v bf_ = *(const short8v*)&Wcv2[fb + nf * 512];
                    acc[nf] = __builtin_amdgcn_mfma_f32_16x16x32_bf16(af, bf_, acc[nf], 0, 0, 0);
                }
            }
        }

    #pragma unroll
    for (int nf = 0; nf < 4; ++nf) {
        int co = nf * 16 + lr;
        float bias = cb[co];
        int h = co >> 5, d = co & 31;
        #pragma unroll
        for (int r = 0; r < 4; ++r) {
            int px = w * 16 + g * 4 + r;
            int n = y0 * 32 + px;
            Kbf[(((size_t)(b * 8 + h) << 10) | n) * 32 + d] = f2bf(acc[nf][r] + bias);
        }
    }
}

// ---------------------------------------------------------------------------
// Kernel 4: MFMA flash attention, LDS-FREE K/V (direct 16B L2 fragment loads,
// zero barriers; only wave-private P LDS). Swapped QK^T, no-max exp2 softmax,
// direct normalized bf16 output. grid (16 qtiles, 32 bh), 4 waves x 16 q rows.
// ---------------------------------------------------------------------------
__global__ __launch_bounds__(256) void attn_mfma5(
    const ushort_t* __restrict__ Qbf, const ushort_t* __restrict__ Kbf,
    const ushort_t* __restrict__ VTbf, ushort_t* __restrict__ AObf)
{
    __shared__ ushort_t Ps[4][16][72];    // wave-private P tiles

    int bh = blockIdx.y, q0 = blockIdx.x * 64;
    int tid = threadIdx.x, w = tid >> 6, l = tid & 63, lr = l & 15, g = l >> 4;

    const ushort_t* Kbase = Kbf + (size_t)bh * 1024 * 32;    // [n][32]
    const ushort_t* Vbase = VTbf + (size_t)bh * 32 * 1024;   // [d][1024]

    short8v qfrag = *(const short8v*)&Qbf[((size_t)bh * 1024 + q0 + w * 16 + lr) * 32 + g * 8];

    f32x4 accO[2] = {};
    float lsum = 0.f;
    const f32x4 zero = {};

    for (int mt = 0; mt < 16; ++mt) {
        int m0 = mt * 64;

        // QK^T: K fragments straight from L2 (row m0+t*16+lr, chans g*8..)
        f32x4 st[4];
        #pragma unroll
        for (int t = 0; t < 4; ++t) {
            short8v kf = *(const short8v*)&Kbase[(size_t)(m0 + t * 16 + lr) * 32 + g * 8];
            st[t] = __builtin_amdgcn_mfma_f32_16x16x32_bf16(kf, qfrag, zero, 0, 0, 0);
        }

        // softmax (exp2 domain, no max), pack P to wave-private LDS
        #pragma unroll
        for (int t = 0; t < 4; ++t) {
            float p0 = exp2f(st[t][0]), p1 = exp2f(st[t][1]);
            float p2 = exp2f(st[t][2]), p3 = exp2f(st[t][3]);
            lsum += (p0 + p1) + (p2 + p3);
            short4v pw;
            pw[0] = (short)f2bf(p0); pw[1] = (short)f2bf(p1);
            pw[2] = (short)f2bf(p2); pw[3] = (short)f2bf(p3);
            *(short4v*)&Ps[w][lr][t * 16 + g * 4] = pw;
        }

        // PV: V fragments straight from L2 (row nt*16+lr, cols m0+kt*32+g*8)
        #pragma unroll
        for (int kt = 0; kt < 2; ++kt) {
            short8v pa = *(const short8v*)&Ps[w][lr][kt * 32 + g * 8];
            #pragma unroll
            for (int nt = 0; nt < 2; ++nt) {
                short8v vb = *(const short8v*)&Vbase[(size_t)(nt * 16 + lr) * 1024 + m0 + kt * 32 + g * 8];
                accO[nt] = __builtin_amdgcn_mfma_f32_16x16x32_bf16(pa, vb, accO[nt], 0, 0, 0);
            }
        }
    }

    // reduce l across the 4 g-groups (lanes sharing q = lr)
    lsum += __shfl_xor(lsum, 16);
    lsum += __shfl_xor(lsum, 32);

    int b = bh >> 3, h = bh & 7;
    #pragma unroll
    for (int r = 0; r < 4; ++r) {
        float lv = __uint_as_float((unsigned)__builtin_amdgcn_ds_bpermute(
            (g * 4 + r) * 4, (int)__float_as_uint(lsum)));
        float inv = 1.0f / lv;
        int n = q0 + w * 16 + g * 4 + r;
        #pragma unroll
        for (int nt = 0; nt < 2; ++nt)
            AObf[((size_t)(b * 1024 + n)) * 256 + h * 32 + nt * 16 + lr] =
                f2bf(accO[nt][r] * inv);
    }
}

// ---------------------------------------------------------------------------
// Kernel 5: output GEMM, LDS-FREE. out = AObf @ Wo + bo (fp32). grid (4,64).
// ---------------------------------------------------------------------------
__global__ __launch_bounds__(256) void out_gemm(
    const ushort_t* __restrict__ A, const ushort_t* __restrict__ WoT,
    const float* __restrict__ bo, float* __restrict__ out)
{
    int colBase = blockIdx.x * 64, rowBase = blockIdx.y * 64;
    int tid = threadIdx.x;
    int w = tid >> 6, l = tid & 63, lr = l & 15, g = l >> 4;
    int wr = w >> 1, wc = w & 1;
    f32x4 acc[2][2] = {};

    const ushort_t* Ar0 = A + (size_t)(rowBase + wr * 32 + lr) * 256 + g * 8;
    const ushort_t* Ar1 = Ar0 + 16 * 256;
    const ushort_t* Br0 = WoT + (size_t)(colBase + wc * 32 + lr) * 256 + g * 8;
    const ushort_t* Br1 = Br0 + 16 * 256;

    #pragma unroll
    for (int k = 0; k < 8; ++k) {
        int kk = k * 32;
        short8v a0 = *(const short8v*)&Ar0[kk];
        short8v a1 = *(const short8v*)&Ar1[kk];
        short8v b0 = *(const short8v*)&Br0[kk];
        short8v b1 = *(const short8v*)&Br1[kk];
        acc[0][0] = __builtin_amdgcn_mfma_f32_16x16x32_bf16(a0, b0, acc[0][0], 0, 0, 0);
        acc[0][1] = __builtin_amdgcn_mfma_f32_16x16x32_bf16(a0, b1, acc[0][1], 0, 0, 0);
        acc[1][0] = __builtin_amdgcn_mfma_f32_16x16x32_bf16(a1, b0, acc[1][0], 0, 0, 0);
        acc[1][1] = __builtin_amdgcn_mfma_f32_16x16x32_bf16(a1, b1, acc[1][1], 0, 0, 0);
    }

    #pragma unroll
    for (int fr = 0; fr < 2; ++fr)
        #pragma unroll
        for (int fc = 0; fc < 2; ++fc) {
            int c = colBase + wc * 32 + fc * 16 + lr;
            float bv = bo[c];
            int nb = rowBase + wr * 32 + fr * 16 + g * 4;
            #pragma unroll
            for (int r = 0; r < 4; ++r)
                out[(size_t)(nb + r) * 256 + c] = acc[fr][fc][r] + bv;
        }
}

// ---------------------------------------------------------------------------
extern "C" void kernel_launch(void* const* d_in, const int* in_sizes, int n_in,
                              void* d_out, int out_size, void* d_ws, size_t ws_size,
                              hipStream_t stream)
{
    const float* src1 = (const float*)d_in[0];
    const float* src2 = (const float*)d_in[1];
    const float* Wq1  = (const float*)d_in[2];
    const float* bq1  = (const float*)d_in[3];
    const float* Wq2  = (const float*)d_in[4];
    const float* bq2  = (const float*)d_in[5];
    const float* Wk   = (const float*)d_in[6];
    const float* bk   = (const float*)d_in[7];
    const float* Wv   = (const float*)d_in[8];
    const float* bv   = (const float*)d_in[9];
    const float* cw   = (const float*)d_in[10];
    const float* cb   = (const float*)d_in[11];
    const float* Wo   = (const float*)d_in[12];
    const float* bo   = (const float*)d_in[13];
    float* out = (float*)d_out;

    char* base = (char*)d_ws;
    const size_t MB = 1u << 20;
    const size_t KB = 1u << 10;
    ushort_t* X1bf = (ushort_t*)(base + 0 * MB);     // 2 MB
    ushort_t* X2bf = (ushort_t*)(base + 2 * MB);     // 2 MB
    ushort_t* Qbf  = (ushort_t*)(base + 4 * MB);     // 2 MB  [32 bh][1024][32]
    ushort_t* Kbf  = (ushort_t*)(base + 6 * MB);     // 2 MB
    ushort_t* VTbf = (ushort_t*)(base + 8 * MB);     // 2 MB  [32 bh][32][1024]
    ushort_t* AObf = (ushort_t*)(base + 10 * MB);    // 2 MB  [4096][256]
    ushort_t* CVbf = (ushort_t*)(base + 12 * MB);    // 512 KB [4096][64]
    ushort_t* WcatT= (ushort_t*)(base + 12 * MB + 512 * KB);   // 384 KB
    ushort_t* WoT  = (ushort_t*)(base + 12 * MB + 896 * KB);   // 128 KB
    float*    bcat = (float*)(base + 13 * MB);                 // 3 KB
    ushort_t* Wcv2 = (ushort_t*)(base + 13 * MB + 4 * KB);     // 72 KB

    pe_prep_kernel<<<1097, 256, 0, stream>>>(
        src1, src2, Wq1, Wq2, Wk, Wv, Wo, cw, bq1, bq2, bk, bv,
        X1bf, X2bf, WcatT, WoT, bcat, Wcv2);
    proj_gemm<<<dim3(12, 64), 256, 0, stream>>>(
        X1bf, X2bf, WcatT, bcat, Qbf, Kbf, VTbf, CVbf);
    conv_mfma<<<64, 256, 0, stream>>>(CVbf, Wcv2, cb, Kbf);
    attn_mfma5<<<dim3(16, 32), 256, 0, stream>>>(Qbf, Kbf, VTbf, AObf);
    out_gemm<<<dim3(4, 64), 256, 0, stream>>>(AObf, WoT, bo, out);
}

// Round 10
// 57.144 us; speedup vs baseline: 9.8258x; 1.0839x over previous
//
#include <hip/hip_runtime.h>
#include <cstdint>
#include <cstddef>

typedef __attribute__((ext_vector_type(8))) short short8v;   // 8 bf16 = 4 VGPRs
typedef __attribute__((ext_vector_type(4))) short short4v;   // 4 bf16 = 8B
typedef __attribute__((ext_vector_type(4))) float f32x4;
typedef unsigned short ushort_t;

__device__ inline unsigned short f2bf(float x) {
    unsigned int u = __float_as_uint(x);
    return (unsigned short)((u + 0x7FFFu + ((u >> 16) & 1u)) >> 16);   // RNE
}

// ---------------------------------------------------------------------------
// Kernel 1: prep (97 blocks).
//  blocks [0,64):  QKVO weight transpose/fold -> WcatT[768][256], WoT, bcat
//  blocks [64,73): conv weight pack -> Wcv2 (72 fragments)
//  blocks [73,97): PE-bias GEMMs: PEW[2][32][768] = T(32x128) @ W_half(128x64cols)
//                  T[p][k] = sin((p+1) * 10000^(-(k&63)/64))
// ---------------------------------------------------------------------------
__global__ __launch_bounds__(256) void prep_kernel(
    const float* __restrict__ Wq1, const float* __restrict__ Wq2,
    const float* __restrict__ Wk, const float* __restrict__ Wv,
    const float* __restrict__ Wo, const float* __restrict__ cw,
    const float* __restrict__ bq1, const float* __restrict__ bq2,
    const float* __restrict__ bk, const float* __restrict__ bv,
    ushort_t* __restrict__ WcatT, ushort_t* __restrict__ WoT,
    float* __restrict__ bcat, ushort_t* __restrict__ Wcv2,
    float* __restrict__ PEW)
{
    __shared__ ushort_t Ts[64][72];
    __shared__ ushort_t Tt[32][136];
    __shared__ ushort_t Bs2[64][136];
    int bx = blockIdx.x;
    int t = threadIdx.x;

    if (bx < 64) {
        int kt = bx & 3, ct = bx >> 2;
        int k0 = kt * 64;
        const float* W; int csrc; int fold = 0; ushort_t* dst; int dstbase;
        if (ct < 2)       { W = Wq1; csrc = ct * 64;        fold = 1; dst = WcatT; dstbase = ct * 64; }
        else if (ct < 4)  { W = Wq2; csrc = (ct - 2) * 64;  fold = 1; dst = WcatT; dstbase = ct * 64; }
        else if (ct < 8)  { W = Wk;  csrc = (ct - 4) * 64;            dst = WcatT; dstbase = ct * 64; }
        else if (ct < 12) { W = Wv;  csrc = (ct - 8) * 64;            dst = WcatT; dstbase = ct * 64; }
        else              { W = Wo;  csrc = (ct - 12) * 64;           dst = WoT;   dstbase = (ct - 12) * 64; }
        if (kt == 0) {
            if (ct == 0 && t < 128) bcat[t] = bq1[t] + bq1[t + 128];
            if (ct == 2 && t < 128) bcat[128 + t] = bq2[t] + bq2[t + 128];
            if (ct == 4) bcat[256 + t] = bk[t];
            if (ct == 8) bcat[512 + t] = bv[t];
        }
        int kr = t >> 2, cq = t & 3;
        #pragma unroll
        for (int i = 0; i < 4; ++i) {
            int cc = cq * 16 + i * 4;
            float4 v = *(const float4*)&W[(size_t)(k0 + kr) * 256 + csrc + cc];
            if (fold) {
                float4 v2 = *(const float4*)&W[(size_t)(k0 + kr) * 256 + csrc + cc + 128];
                v.x += v2.x; v.y += v2.y; v.z += v2.z; v.w += v2.w;
            }
            Ts[kr][cc + 0] = f2bf(v.x); Ts[kr][cc + 1] = f2bf(v.y);
            Ts[kr][cc + 2] = f2bf(v.z); Ts[kr][cc + 3] = f2bf(v.w);
        }
        __syncthreads();
        int cr = t >> 2, kq = t & 3;
        ushort_t tmp[16];
        #pragma unroll
        for (int i = 0; i < 16; ++i) tmp[i] = Ts[kq * 16 + i][cr];
        *(short8v*)&dst[(size_t)(dstbase + cr) * 256 + k0 + kq * 16]     = *(short8v*)&tmp[0];
        *(short8v*)&dst[(size_t)(dstbase + cr) * 256 + k0 + kq * 16 + 8] = *(short8v*)&tmp[8];
        return;
    }

    if (bx < 73) {
        int tap = bx - 64;
        int ci = t >> 2, co0 = (t & 3) * 16;
        #pragma unroll
        for (int i = 0; i < 16; ++i)
            Ts[ci][co0 + i] = f2bf(cw[((size_t)(tap * 64 + ci)) * 64 + co0 + i]);
        __syncthreads();
        int co = t >> 2, ci0 = (t & 3) * 16;
        ushort_t tmp[16];
        #pragma unroll
        for (int i = 0; i < 16; ++i) tmp[i] = Ts[ci0 + i][co];
        int kh = ci0 >> 5;
        int f = (tap * 2 + kh) * 4 + (co >> 4);
        int off = f * 512 + (co & 15) * 32 + (ci0 & 31);
        *(short8v*)&Wcv2[off]     = *(short8v*)&tmp[0];
        *(short8v*)&Wcv2[off + 8] = *(short8v*)&tmp[8];
        return;
    }

    // ---- PE-bias GEMM blocks ----
    {
        int pidx = bx - 73;
        int half = pidx / 12, ct2 = pidx % 12;
        const float* W; int csrc; int fold = 0;
        if (ct2 < 2)      { W = Wq1; csrc = ct2 * 64;       fold = 1; }
        else if (ct2 < 4) { W = Wq2; csrc = (ct2 - 2) * 64; fold = 1; }
        else if (ct2 < 8) { W = Wk;  csrc = (ct2 - 4) * 64; }
        else              { W = Wv;  csrc = (ct2 - 8) * 64; }

        // build analytic T (32 pos x 128 chans)
        #pragma unroll
        for (int j = 0; j < 16; ++j) {
            int idx2 = t * 16 + j;
            int p = idx2 >> 7, k = idx2 & 127;
            float freq = expf(-0.14391156831212787f * (float)(k & 63));
            Tt[p][k] = f2bf(sinf((float)(p + 1) * freq));
        }
        // stage W rows [half*128 .. +128) x 64 cols, transposed -> Bs2[c][k]
        #pragma unroll
        for (int i = 0; i < 2; ++i) {
            int k = (t >> 2) + i * 64;
            int cbase = (t & 3) * 16;
            #pragma unroll
            for (int j2 = 0; j2 < 4; ++j2) {
                float4 v = *(const float4*)&W[(size_t)(half * 128 + k) * 256 + csrc + cbase + j2 * 4];
                if (fold) {
                    float4 v2 = *(const float4*)&W[(size_t)(half * 128 + k) * 256 + csrc + cbase + j2 * 4 + 128];
                    v.x += v2.x; v.y += v2.y; v.z += v2.z; v.w += v2.w;
                }
                Bs2[cbase + j2 * 4 + 0][k] = f2bf(v.x);
                Bs2[cbase + j2 * 4 + 1][k] = f2bf(v.y);
                Bs2[cbase + j2 * 4 + 2][k] = f2bf(v.z);
                Bs2[cbase + j2 * 4 + 3][k] = f2bf(v.w);
            }
        }
        __syncthreads();

        int w = t >> 6, l = t & 63, lr = l & 15, g = l >> 4;
        int mrow = w >> 1, cw2 = w & 1;
        f32x4 acc2[2] = {};
        #pragma unroll
        for (int ks = 0; ks < 4; ++ks) {
            short8v af = *(const short8v*)&Tt[mrow * 16 + lr][ks * 32 + g * 8];
            #pragma unroll
            for (int fc = 0; fc < 2; ++fc) {
                short8v bf_ = *(const short8v*)&Bs2[cw2 * 32 + fc * 16 + lr][ks * 32 + g * 8];
                acc2[fc] = __builtin_amdgcn_mfma_f32_16x16x32_bf16(af, bf_, acc2[fc], 0, 0, 0);
            }
        }
        #pragma unroll
        for (int fc = 0; fc < 2; ++fc)
            #pragma unroll
            for (int r = 0; r < 4; ++r) {
                int p = mrow * 16 + g * 4 + r;
                int c = ct2 * 64 + cw2 * 32 + fc * 16 + lr;
                PEW[half * 24576 + p * 768 + c] = acc2[fc][r];
            }
    }
}

// ---------------------------------------------------------------------------
// Kernel 2: merged projection GEMM (LDS-staged, R7 structure).
// A staged from src fp32 -> bf16 (no PE in A); PE added in epilogue via PEW.
// grid (12, 64); 64x64 tile, BK=128, 4 waves.
// ---------------------------------------------------------------------------
__global__ __launch_bounds__(256) void proj_gemm(
    const float* __restrict__ src1, const float* __restrict__ src2,
    const ushort_t* __restrict__ WcatT, const float* __restrict__ bcat,
    const float* __restrict__ PEW,
    ushort_t* __restrict__ Qbf, ushort_t* __restrict__ Kbf,
    ushort_t* __restrict__ VTbf, ushort_t* __restrict__ CVbf)
{
    __shared__ ushort_t As[64][136];
    __shared__ ushort_t Bs[64][136];
    int colBase = blockIdx.x * 64, rowBase = blockIdx.y * 64;
    const float* A = (colBase >= 128 && colBase < 256) ? src2 : src1;
    int tid = threadIdx.x;
    int w = tid >> 6, l = tid & 63, lr = l & 15, g = l >> 4;
    int wr = w >> 1, wc = w & 1;
    int tr = tid >> 2, tq = tid & 3;
    f32x4 acc[2][2] = {};

    for (int kb = 0; kb < 256; kb += 128) {
        #pragma unroll
        for (int i = 0; i < 4; ++i) {
            const float* ap = &A[(size_t)(rowBase + tr) * 256 + kb + tq * 32 + i * 8];
            float4 v0 = *(const float4*)ap;
            float4 v1 = *(const float4*)(ap + 4);
            ushort_t tmp8[8] = {f2bf(v0.x), f2bf(v0.y), f2bf(v0.z), f2bf(v0.w),
                                f2bf(v1.x), f2bf(v1.y), f2bf(v1.z), f2bf(v1.w)};
            *(short8v*)&As[tr][tq * 32 + i * 8] = *(short8v*)tmp8;
        }
        #pragma unroll
        for (int i = 0; i < 4; ++i)
            *(short8v*)&Bs[tr][tq * 32 + i * 8] =
                *(const short8v*)&WcatT[(size_t)(colBase + tr) * 256 + kb + tq * 32 + i * 8];
        __syncthreads();
        #pragma unroll
        for (int ks = 0; ks < 4; ++ks) {
            short8v a0 = *(const short8v*)&As[wr * 32 + lr][ks * 32 + g * 8];
            short8v a1 = *(const short8v*)&As[wr * 32 + 16 + lr][ks * 32 + g * 8];
            short8v b0 = *(const short8v*)&Bs[wc * 32 + lr][ks * 32 + g * 8];
            short8v b1 = *(const short8v*)&Bs[wc * 32 + 16 + lr][ks * 32 + g * 8];
            acc[0][0] = __builtin_amdgcn_mfma_f32_16x16x32_bf16(a0, b0, acc[0][0], 0, 0, 0);
            acc[0][1] = __builtin_amdgcn_mfma_f32_16x16x32_bf16(a0, b1, acc[0][1], 0, 0, 0);
            acc[1][0] = __builtin_amdgcn_mfma_f32_16x16x32_bf16(a1, b0, acc[1][0], 0, 0, 0);
            acc[1][1] = __builtin_amdgcn_mfma_f32_16x16x32_bf16(a1, b1, acc[1][1], 0, 0, 0);
        }
        __syncthreads();
    }

    const float scale = 0.25503532182457352f;   // log2(e)/sqrt(32)
    #pragma unroll
    for (int fr = 0; fr < 2; ++fr)
        #pragma unroll
        for (int fc = 0; fc < 2; ++fc) {
            int c = colBase + wc * 32 + fc * 16 + lr;
            float bv = bcat[c];
            int nb = rowBase + wr * 32 + fr * 16 + g * 4;
            int b = nb >> 10;
            int nn = nb & 1023;
            float pey = PEW[(nn >> 5) * 768 + c];            // PYW[row][c]
            if (c < 512) {
                #pragma unroll
                for (int r = 0; r < 4; ++r) {
                    int n = nb + r;
                    float pex = PEW[24576 + ((nn & 31) + r) * 768 + c];  // PXW[col][c]
                    float v = acc[fr][fc][r] + bv + pey + pex;
                    if (c < 128) {
                        int h = 4 + (c >> 5), d = c & 31;
                        Qbf[(((size_t)(b * 8 + h) << 10) | (n & 1023)) * 32 + d] = f2bf(v * scale);
                    } else if (c < 256) {
                        int c2 = c - 128;
                        int h = c2 >> 5, d = c2 & 31;
                        Qbf[(((size_t)(b * 8 + h) << 10) | (n & 1023)) * 32 + d] = f2bf(v * scale);
                    } else {
                        int c3 = c - 256;
                        if (c3 < 128) {
                            int h = 4 + (c3 >> 5), d = c3 & 31;
                            Kbf[(((size_t)(b * 8 + h) << 10) | (n & 1023)) * 32 + d] = f2bf(v);
                        } else if (c3 < 192) {
                            CVbf[(size_t)n * 64 + (c3 - 128)] = f2bf(v);
                        } else {
                            int h = 2 + ((c3 - 192) >> 5), d = c3 & 31;
                            Kbf[(((size_t)(b * 8 + h) << 10) | (n & 1023)) * 32 + d] = f2bf(v);
                        }
                    }
                }
            } else {
                int c4 = c - 512;
                int h = c4 >> 5, d = c4 & 31;
                short4v pk;
                #pragma unroll
                for (int r = 0; r < 4; ++r) {
                    float pex = PEW[24576 + ((nn & 31) + r) * 768 + c];
                    pk[r] = (short)f2bf(acc[fr][fc][r] + bv + pey + pex);
                }
                *(short4v*)&VTbf[((size_t)((b * 8 + h) * 32 + d)) * 1024 + (nb & 1023)] = pk;
            }
        }
}

// ---------------------------------------------------------------------------
// Kernel 3: 3x3 SAME conv as MFMA implicit GEMM (64 blocks). (unchanged)
// ---------------------------------------------------------------------------
__global__ __launch_bounds__(256) void conv_mfma(
    const ushort_t* __restrict__ CVbf, const ushort_t* __restrict__ Wcv2,
    const float* __restrict__ cb, ushort_t* __restrict__ Kbf)
{
    __shared__ ushort_t Xs[8704];          // 4*34*64
    int blk = blockIdx.x;
    int b = blk >> 4, y0 = (blk & 15) * 2;
    int tid = threadIdx.x, w = tid >> 6, l = tid & 63, lr = l & 15, g = l >> 4;

    for (int p = tid >> 1; p < 136; p += 128) {
        int ry = p / 34, xc = p % 34;
        int ci0 = (tid & 1) * 32;
        int gy = y0 - 1 + ry, gx = xc - 1;
        int base = p << 6;
        int sw = (xc & 7) << 3;
        if ((unsigned)gy < 32u && (unsigned)gx < 32u) {
            const ushort_t* src = &CVbf[((size_t)(b * 1024 + gy * 32 + gx)) * 64 + ci0];
            #pragma unroll
            for (int k = 0; k < 4; ++k)
                *(short8v*)&Xs[(base + ci0 + k * 8) ^ sw] = *(const short8v*)&src[k * 8];
        } else {
            short8v z = {};
            #pragma unroll
            for (int k = 0; k < 4; ++k)
                *(short8v*)&Xs[(base + ci0 + k * 8) ^ sw] = z;
        }
    }
    __syncthreads();

    int yl = w >> 1, xb = (w & 1) * 16;
    f32x4 acc[4] = {};
    #pragma unroll
    for (int ky = 0; ky < 3; ++ky)
        #pragma unroll
        for (int kx = 0; kx < 3; ++kx) {
            int tap = ky * 3 + kx;
            #pragma unroll
            for (int kh = 0; kh < 2; ++kh) {
                int xa = xb + lr + kx;
                int e = (((yl + ky) * 34 + xa) << 6) + kh * 32 + g * 8;
                short8v af = *(const short8v*)&Xs[e ^ ((xa & 7) << 3)];
                int fb = (tap * 2 + kh) * 4 * 512 + lr * 32 + g * 8;
                #pragma unroll
                for (int nf = 0; nf < 4; ++nf) {
                    short8v bf_ = *(const short8v*)&Wcv2[fb + nf * 512];
                    acc[nf] = __builtin_amdgcn_mfma_f32_16x16x32_bf16(af, bf_, acc[nf], 0, 0, 0);
                }
            }
        }

    #pragma unroll
    for (int nf = 0; nf < 4; ++nf) {
        int co = nf * 16 + lr;
        float bias = cb[co];
        int h = co >> 5, d = co & 31;
        #pragma unroll
        for (int r = 0; r < 4; ++r) {
            int px = w * 16 + g * 4 + r;
            int n = y0 * 32 + px;
            Kbf[(((size_t)(b * 8 + h) << 10) | n) * 32 + d] = f2bf(acc[nf][r] + bias);
        }
    }
}

// ---------------------------------------------------------------------------
// Kernel 4: MFMA flash attention (R7 structure: split=1, dbuf K/V, 1 barrier
// per tile, swapped QK^T, no-max exp2 softmax) + s_setprio around MFMA.
// grid (16 qtiles, 32 bh), 4 waves x 16 q rows.
// ---------------------------------------------------------------------------
__global__ __launch_bounds__(256) void attn_mfma4(
    const ushort_t* __restrict__ Qbf, const ushort_t* __restrict__ Kbf,
    const ushort_t* __restrict__ VTbf, ushort_t* __restrict__ AObf)
{
    __shared__ ushort_t Kt[2][64][32];
    __shared__ ushort_t VT[2][32][72];
    __shared__ ushort_t Ps[4][16][72];

    int bh = blockIdx.y, q0 = blockIdx.x * 64;
    int tid = threadIdx.x, w = tid >> 6, l = tid & 63, lr = l & 15, g = l >> 4;
    int vd = tid >> 3, vn = (tid & 7) * 8;

    short8v qfrag = *(const short8v*)&Qbf[((size_t)bh * 1024 + q0 + w * 16 + lr) * 32 + g * 8];

    f32x4 accO[2] = {};
    float lsum = 0.f;
    const f32x4 zero = {};

    ((short8v*)&Kt[0][0][0])[tid] =
        *(const short8v*)&Kbf[((size_t)bh * 1024) * 32 + tid * 8];
    *(short8v*)&VT[0][vd][vn] =
        *(const short8v*)&VTbf[((size_t)bh * 32 + vd) * 1024 + vn];

    for (int mt = 0; mt < 16; ++mt) {
        int cur = mt & 1, nb = cur ^ 1;
        __syncthreads();

        short8v kreg, vreg;
        bool hasNext = (mt + 1) < 16;
        if (hasNext) {
            int m1 = (mt + 1) * 64;
            kreg = *(const short8v*)&Kbf[((size_t)bh * 1024 + m1) * 32 + tid * 8];
            vreg = *(const short8v*)&VTbf[((size_t)bh * 32 + vd) * 1024 + m1 + vn];
        }

        f32x4 st[4];
        __builtin_amdgcn_s_setprio(1);
        #pragma unroll
        for (int t = 0; t < 4; ++t) {
            short8v kf = *(const short8v*)&Kt[cur][t * 16 + lr][g * 8];
            st[t] = __builtin_amdgcn_mfma_f32_16x16x32_bf16(kf, qfrag, zero, 0, 0, 0);
        }
        __builtin_amdgcn_s_setprio(0);

        #pragma unroll
        for (int t = 0; t < 4; ++t) {
            float p0 = exp2f(st[t][0]), p1 = exp2f(st[t][1]);
            float p2 = exp2f(st[t][2]), p3 = exp2f(st[t][3]);
            lsum += (p0 + p1) + (p2 + p3);
            short4v pw;
            pw[0] = (short)f2bf(p0); pw[1] = (short)f2bf(p1);
            pw[2] = (short)f2bf(p2); pw[3] = (short)f2bf(p3);
            *(short4v*)&Ps[w][lr][t * 16 + g * 4] = pw;
        }

        __builtin_amdgcn_s_setprio(1);
        #pragma unroll
        for (int kt = 0; kt < 2; ++kt) {
            short8v pa = *(const short8v*)&Ps[w][lr][kt * 32 + g * 8];
            #pragma unroll
            for (int nt = 0; nt < 2; ++nt) {
                short8v vb = *(const short8v*)&VT[cur][nt * 16 + lr][kt * 32 + g * 8];
                accO[nt] = __builtin_amdgcn_mfma_f32_16x16x32_bf16(pa, vb, accO[nt], 0, 0, 0);
            }
        }
        __builtin_amdgcn_s_setprio(0);

        if (hasNext) {
            ((short8v*)&Kt[nb][0][0])[tid] = kreg;
            *(short8v*)&VT[nb][vd][vn] = vreg;
        }
    }

    lsum += __shfl_xor(lsum, 16);
    lsum += __shfl_xor(lsum, 32);

    int b = bh >> 3, h = bh & 7;
    #pragma unroll
    for (int r = 0; r < 4; ++r) {
        float lv = __uint_as_float((unsigned)__builtin_amdgcn_ds_bpermute(
            (g * 4 + r) * 4, (int)__float_as_uint(lsum)));
        float inv = 1.0f / lv;
        int n = q0 + w * 16 + g * 4 + r;
        #pragma unroll
        for (int nt = 0; nt < 2; ++nt)
            AObf[((size_t)(b * 1024 + n)) * 256 + h * 32 + nt * 16 + lr] =
                f2bf(accO[nt][r] * inv);
    }
}

// ---------------------------------------------------------------------------
// Kernel 5: output GEMM  out = AObf @ Wo + bo (fp32 out). grid (4,64).
// ---------------------------------------------------------------------------
__global__ __launch_bounds__(256) void out_gemm(
    const ushort_t* __restrict__ A, const ushort_t* __restrict__ WoT,
    const float* __restrict__ bo, float* __restrict__ out)
{
    __shared__ ushort_t As[64][136];
    __shared__ ushort_t Bs[64][136];
    int colBase = blockIdx.x * 64, rowBase = blockIdx.y * 64;
    int tid = threadIdx.x;
    int w = tid >> 6, l = tid & 63, lr = l & 15, g = l >> 4;
    int wr = w >> 1, wc = w & 1;
    int tr = tid >> 2, tq = tid & 3;
    f32x4 acc[2][2] = {};

    for (int kb = 0; kb < 256; kb += 128) {
        #pragma unroll
        for (int i = 0; i < 4; ++i)
            *(short8v*)&As[tr][tq * 32 + i * 8] =
                *(const short8v*)&A[(size_t)(rowBase + tr) * 256 + kb + tq * 32 + i * 8];
        #pragma unroll
        for (int i = 0; i < 4; ++i)
            *(short8v*)&Bs[tr][tq * 32 + i * 8] =
                *(const short8v*)&WoT[(size_t)(colBase + tr) * 256 + kb + tq * 32 + i * 8];
        __syncthreads();
        #pragma unroll
        for (int ks = 0; ks < 4; ++ks) {
            short8v a0 = *(const short8v*)&As[wr * 32 + lr][ks * 32 + g * 8];
            short8v a1 = *(const short8v*)&As[wr * 32 + 16 + lr][ks * 32 + g * 8];
            short8v b0 = *(const short8v*)&Bs[wc * 32 + lr][ks * 32 + g * 8];
            short8v b1 = *(const short8v*)&Bs[wc * 32 + 16 + lr][ks * 32 + g * 8];
            acc[0][0] = __builtin_amdgcn_mfma_f32_16x16x32_bf16(a0, b0, acc[0][0], 0, 0, 0);
            acc[0][1] = __builtin_amdgcn_mfma_f32_16x16x32_bf16(a0, b1, acc[0][1], 0, 0, 0);
            acc[1][0] = __builtin_amdgcn_mfma_f32_16x16x32_bf16(a1, b0, acc[1][0], 0, 0, 0);
            acc[1][1] = __builtin_amdgcn_mfma_f32_16x16x32_bf16(a1, b1, acc[1][1], 0, 0, 0);
        }
        __syncthreads();
    }

    #pragma unroll
    for (int fr = 0; fr < 2; ++fr)
        #pragma unroll
        for (int fc = 0; fc < 2; ++fc) {
            int c = colBase + wc * 32 + fc * 16 + lr;
            float bv = bo[c];
            int nb = rowBase + wr * 32 + fr * 16 + g * 4;
            #pragma unroll
            for (int r = 0; r < 4; ++r)
                out[(size_t)(nb + r) * 256 + c] = acc[fr][fc][r] + bv;
        }
}

// ---------------------------------------------------------------------------
extern "C" void kernel_launch(void* const* d_in, const int* in_sizes, int n_in,
                              void* d_out, int out_size, void* d_ws, size_t ws_size,
                              hipStream_t stream)
{
    const float* src1 = (const float*)d_in[0];
    const float* src2 = (const float*)d_in[1];
    const float* Wq1  = (const float*)d_in[2];
    const float* bq1  = (const float*)d_in[3];
    const float* Wq2  = (const float*)d_in[4];
    const float* bq2  = (const float*)d_in[5];
    const float* Wk   = (const float*)d_in[6];
    const float* bk   = (const float*)d_in[7];
    const float* Wv   = (const float*)d_in[8];
    const float* bv   = (const float*)d_in[9];
    const float* cw   = (const float*)d_in[10];
    const float* cb   = (const float*)d_in[11];
    const float* Wo   = (const float*)d_in[12];
    const float* bo   = (const float*)d_in[13];
    float* out = (float*)d_out;

    char* base = (char*)d_ws;
    const size_t MB = 1u << 20;
    const size_t KB = 1u << 10;
    ushort_t* Qbf  = (ushort_t*)(base + 0 * MB);     // 2 MB  [32 bh][1024][32]
    ushort_t* Kbf  = (ushort_t*)(base + 2 * MB);     // 2 MB
    ushort_t* VTbf = (ushort_t*)(base + 4 * MB);     // 2 MB  [32 bh][32][1024]
    ushort_t* AObf = (ushort_t*)(base + 6 * MB);     // 2 MB  [4096][256]
    ushort_t* CVbf = (ushort_t*)(base + 8 * MB);     // 512 KB [4096][64]
    ushort_t* WcatT= (ushort_t*)(base + 8 * MB + 512 * KB);   // 384 KB
    ushort_t* WoT  = (ushort_t*)(base + 8 * MB + 896 * KB);   // 128 KB
    float*    bcat = (float*)(base + 9 * MB);                 // 3 KB
    ushort_t* Wcv2 = (ushort_t*)(base + 9 * MB + 4 * KB);     // 72 KB
    float*    PEW  = (float*)(base + 9 * MB + 128 * KB);      // 192 KB [2][32][768]

    prep_kernel<<<97, 256, 0, stream>>>(
        Wq1, Wq2, Wk, Wv, Wo, cw, bq1, bq2, bk, bv,
        WcatT, WoT, bcat, Wcv2, PEW);
    proj_gemm<<<dim3(12, 64), 256, 0, stream>>>(
        src1, src2, WcatT, bcat, PEW, Qbf, Kbf, VTbf, CVbf);
    conv_mfma<<<64, 256, 0, stream>>>(CVbf, Wcv2, cb, Kbf);
    attn_mfma4<<<dim3(16, 32), 256, 0, stream>>>(Qbf, Kbf, VTbf, AObf);
    out_gemm<<<dim3(4, 64), 256, 0, stream>>>(AObf, WoT, bo, out);
}

// Round 11
// 47.769 us; speedup vs baseline: 11.7541x; 1.1962x over previous
//
#include <hip/hip_runtime.h>
#include <cstdint>
#include <cstddef>

typedef __attribute__((ext_vector_type(8))) short short8v;   // 8 bf16 = 4 VGPRs
typedef __attribute__((ext_vector_type(4))) short short4v;   // 4 bf16 = 8B
typedef __attribute__((ext_vector_type(4))) float f32x4;
typedef unsigned short ushort_t;

__device__ inline unsigned short f2bf(float x) {
    unsigned int u = __float_as_uint(x);
    return (unsigned short)((u + 0x7FFFu + ((u >> 16) & 1u)) >> 16);   // RNE
}

// HW paired conversion: lo -> bits[15:0], hi -> bits[31:16], RNE (gfx950)
__device__ inline unsigned int cvtpk_bf16(float lo, float hi) {
    unsigned int r;
    asm("v_cvt_pk_bf16_f32 %0, %1, %2" : "=v"(r) : "v"(lo), "v"(hi));
    return r;
}

// ---------------------------------------------------------------------------
// Kernel 1 (fused): blocks [0,1024): X1/X2 = bf16(src + pe)
//                   blocks [1024,1088): QKVO weight transpose/fold prep
//                   blocks [1088,1097): conv weight pack (per tap)
// ---------------------------------------------------------------------------
__global__ __launch_bounds__(256) void pe_prep_kernel(
    const float* __restrict__ src1, const float* __restrict__ src2,
    const float* __restrict__ Wq1, const float* __restrict__ Wq2,
    const float* __restrict__ Wk, const float* __restrict__ Wv,
    const float* __restrict__ Wo, const float* __restrict__ cw,
    const float* __restrict__ bq1, const float* __restrict__ bq2,
    const float* __restrict__ bk, const float* __restrict__ bv,
    ushort_t* __restrict__ X1, ushort_t* __restrict__ X2,
    ushort_t* __restrict__ WcatT, ushort_t* __restrict__ WoT,
    float* __restrict__ bcat, ushort_t* __restrict__ Wcv2)
{
    __shared__ ushort_t Ts[64][72];
    int bx = blockIdx.x;
    int t = threadIdx.x;

    if (bx < 1024) {
        int n = bx, c = t;
        int row = n >> 5, col = n & 31;
        float pos = (c < 128) ? (float)(row + 1) : (float)(col + 1);
        float freq = expf(-0.14391156831212787f * (float)(c & 63));
        float pe = sinf(pos * freq);
        for (int b = 0; b < 4; ++b) {
            size_t idx = ((size_t)b * 1024 + n) * 256 + c;
            unsigned int u = cvtpk_bf16(src1[idx] + pe, src2[idx] + pe);
            X1[idx] = (ushort_t)(u & 0xFFFFu);
            X2[idx] = (ushort_t)(u >> 16);
        }
        return;
    }

    if (bx < 1088) {
        int idx = bx - 1024;
        int kt = idx & 3, ct = idx >> 2;
        int k0 = kt * 64;
        const float* W; int csrc; int fold = 0; ushort_t* dst; int dstbase;
        if (ct < 2)       { W = Wq1; csrc = ct * 64;        fold = 1; dst = WcatT; dstbase = ct * 64; }
        else if (ct < 4)  { W = Wq2; csrc = (ct - 2) * 64;  fold = 1; dst = WcatT; dstbase = ct * 64; }
        else if (ct < 8)  { W = Wk;  csrc = (ct - 4) * 64;            dst = WcatT; dstbase = ct * 64; }
        else if (ct < 12) { W = Wv;  csrc = (ct - 8) * 64;            dst = WcatT; dstbase = ct * 64; }
        else              { W = Wo;  csrc = (ct - 12) * 64;           dst = WoT;   dstbase = (ct - 12) * 64; }
        if (kt == 0) {
            if (ct == 0 && t < 128) bcat[t] = bq1[t] + bq1[t + 128];
            if (ct == 2 && t < 128) bcat[128 + t] = bq2[t] + bq2[t + 128];
            if (ct == 4) bcat[256 + t] = bk[t];
            if (ct == 8) bcat[512 + t] = bv[t];
        }

        int kr = t >> 2, cq = t & 3;
        #pragma unroll
        for (int i = 0; i < 4; ++i) {
            int cc = cq * 16 + i * 4;
            float4 v = *(const float4*)&W[(size_t)(k0 + kr) * 256 + csrc + cc];
            if (fold) {
                float4 v2 = *(const float4*)&W[(size_t)(k0 + kr) * 256 + csrc + cc + 128];
                v.x += v2.x; v.y += v2.y; v.z += v2.z; v.w += v2.w;
            }
            unsigned int u01 = cvtpk_bf16(v.x, v.y);
            unsigned int u23 = cvtpk_bf16(v.z, v.w);
            Ts[kr][cc + 0] = (ushort_t)(u01 & 0xFFFFu); Ts[kr][cc + 1] = (ushort_t)(u01 >> 16);
            Ts[kr][cc + 2] = (ushort_t)(u23 & 0xFFFFu); Ts[kr][cc + 3] = (ushort_t)(u23 >> 16);
        }
        __syncthreads();
        int cr = t >> 2, kq = t & 3;
        ushort_t tmp[16];
        #pragma unroll
        for (int i = 0; i < 16; ++i) tmp[i] = Ts[kq * 16 + i][cr];
        *(short8v*)&WcatT[0] ; // no-op to keep compiler honest (never executed path removed)
        *(short8v*)&dst[(size_t)(dstbase + cr) * 256 + k0 + kq * 16]     = *(short8v*)&tmp[0];
        *(short8v*)&dst[(size_t)(dstbase + cr) * 256 + k0 + kq * 16 + 8] = *(short8v*)&tmp[8];
        return;
    }

    {
        int tap = bx - 1088;
        int ci = t >> 2, co0 = (t & 3) * 16;
        #pragma unroll
        for (int i = 0; i < 16; ++i)
            Ts[ci][co0 + i] = f2bf(cw[((size_t)(tap * 64 + ci)) * 64 + co0 + i]);
        __syncthreads();
        int co = t >> 2, ci0 = (t & 3) * 16;
        ushort_t tmp[16];
        #pragma unroll
        for (int i = 0; i < 16; ++i) tmp[i] = Ts[ci0 + i][co];
        int kh = ci0 >> 5;
        int f = (tap * 2 + kh) * 4 + (co >> 4);
        int off = f * 512 + (co & 15) * 32 + (ci0 & 31);
        *(short8v*)&Wcv2[off]     = *(short8v*)&tmp[0];
        *(short8v*)&Wcv2[off + 8] = *(short8v*)&tmp[8];
    }
}

// ---------------------------------------------------------------------------
// Kernel 2: merged projection GEMM. grid (12, 64); 64x64 tile, BK=128, 4 waves.
// ---------------------------------------------------------------------------
__global__ __launch_bounds__(256) void proj_gemm(
    const ushort_t* __restrict__ X1, const ushort_t* __restrict__ X2,
    const ushort_t* __restrict__ WcatT, const float* __restrict__ bcat,
    ushort_t* __restrict__ Qbf, ushort_t* __restrict__ Kbf,
    ushort_t* __restrict__ VTbf, ushort_t* __restrict__ CVbf)
{
    __shared__ ushort_t As[64][136];
    __shared__ ushort_t Bs[64][136];
    int colBase = blockIdx.x * 64, rowBase = blockIdx.y * 64;
    const ushort_t* A = (colBase >= 128 && colBase < 256) ? X2 : X1;
    int tid = threadIdx.x;
    int w = tid >> 6, l = tid & 63, lr = l & 15, g = l >> 4;
    int wr = w >> 1, wc = w & 1;
    int tr = tid >> 2, tq = tid & 3;
    f32x4 acc[2][2] = {};

    for (int kb = 0; kb < 256; kb += 128) {
        #pragma unroll
        for (int i = 0; i < 4; ++i)
            *(short8v*)&As[tr][tq * 32 + i * 8] =
                *(const short8v*)&A[(size_t)(rowBase + tr) * 256 + kb + tq * 32 + i * 8];
        #pragma unroll
        for (int i = 0; i < 4; ++i)
            *(short8v*)&Bs[tr][tq * 32 + i * 8] =
                *(const short8v*)&WcatT[(size_t)(colBase + tr) * 256 + kb + tq * 32 + i * 8];
        __syncthreads();
        #pragma unroll
        for (int ks = 0; ks < 4; ++ks) {
            short8v a0 = *(const short8v*)&As[wr * 32 + lr][ks * 32 + g * 8];
            short8v a1 = *(const short8v*)&As[wr * 32 + 16 + lr][ks * 32 + g * 8];
            short8v b0 = *(const short8v*)&Bs[wc * 32 + lr][ks * 32 + g * 8];
            short8v b1 = *(const short8v*)&Bs[wc * 32 + 16 + lr][ks * 32 + g * 8];
            acc[0][0] = __builtin_amdgcn_mfma_f32_16x16x32_bf16(a0, b0, acc[0][0], 0, 0, 0);
            acc[0][1] = __builtin_amdgcn_mfma_f32_16x16x32_bf16(a0, b1, acc[0][1], 0, 0, 0);
            acc[1][0] = __builtin_amdgcn_mfma_f32_16x16x32_bf16(a1, b0, acc[1][0], 0, 0, 0);
            acc[1][1] = __builtin_amdgcn_mfma_f32_16x16x32_bf16(a1, b1, acc[1][1], 0, 0, 0);
        }
        __syncthreads();
    }

    const float scale = 0.25503532182457352f;   // log2(e)/sqrt(32)
    #pragma unroll
    for (int fr = 0; fr < 2; ++fr)
        #pragma unroll
        for (int fc = 0; fc < 2; ++fc) {
            int c = colBase + wc * 32 + fc * 16 + lr;
            float bv = bcat[c];
            int nb = rowBase + wr * 32 + fr * 16 + g * 4;
            int b = nb >> 10;
            float vv[4];
            #pragma unroll
            for (int r = 0; r < 4; ++r) vv[r] = acc[fr][fc][r] + bv;
            if (c < 256) {
                #pragma unroll
                for (int r = 0; r < 4; ++r) vv[r] *= scale;
            }
            unsigned int u01 = cvtpk_bf16(vv[0], vv[1]);
            unsigned int u23 = cvtpk_bf16(vv[2], vv[3]);
            ushort_t sv[4] = {(ushort_t)(u01 & 0xFFFFu), (ushort_t)(u01 >> 16),
                              (ushort_t)(u23 & 0xFFFFu), (ushort_t)(u23 >> 16)};
            if (c < 512) {
                #pragma unroll
                for (int r = 0; r < 4; ++r) {
                    int n = nb + r;
                    if (c < 128) {
                        int h = 4 + (c >> 5), d = c & 31;
                        Qbf[(((size_t)(b * 8 + h) << 10) | (n & 1023)) * 32 + d] = sv[r];
                    } else if (c < 256) {
                        int c2 = c - 128;
                        int h = c2 >> 5, d = c2 & 31;
                        Qbf[(((size_t)(b * 8 + h) << 10) | (n & 1023)) * 32 + d] = sv[r];
                    } else {
                        int c3 = c - 256;
                        if (c3 < 128) {
                            int h = 4 + (c3 >> 5), d = c3 & 31;
                            Kbf[(((size_t)(b * 8 + h) << 10) | (n & 1023)) * 32 + d] = sv[r];
                        } else if (c3 < 192) {
                            CVbf[(size_t)n * 64 + (c3 - 128)] = sv[r];
                        } else {
                            int h = 2 + ((c3 - 192) >> 5), d = c3 & 31;
                            Kbf[(((size_t)(b * 8 + h) << 10) | (n & 1023)) * 32 + d] = sv[r];
                        }
                    }
                }
            } else {
                int c4 = c - 512;
                int h = c4 >> 5, d = c4 & 31;
                uint2 pk;
                pk.x = u01; pk.y = u23;
                *(uint2*)&VTbf[((size_t)((b * 8 + h) * 32 + d)) * 1024 + (nb & 1023)] = pk;
            }
        }
}

// ---------------------------------------------------------------------------
// Kernel 3: 3x3 SAME conv as MFMA implicit GEMM (64 blocks).
// ---------------------------------------------------------------------------
__global__ __launch_bounds__(256) void conv_mfma(
    const ushort_t* __restrict__ CVbf, const ushort_t* __restrict__ Wcv2,
    const float* __restrict__ cb, ushort_t* __restrict__ Kbf)
{
    __shared__ ushort_t Xs[8704];          // 4*34*64
    int blk = blockIdx.x;
    int b = blk >> 4, y0 = (blk & 15) * 2;
    int tid = threadIdx.x, w = tid >> 6, l = tid & 63, lr = l & 15, g = l >> 4;

    for (int p = tid >> 1; p < 136; p += 128) {
        int ry = p / 34, xc = p % 34;
        int ci0 = (tid & 1) * 32;
        int gy = y0 - 1 + ry, gx = xc - 1;
        int base = p << 6;
        int sw = (xc & 7) << 3;
        if ((unsigned)gy < 32u && (unsigned)gx < 32u) {
            const ushort_t* src = &CVbf[((size_t)(b * 1024 + gy * 32 + gx)) * 64 + ci0];
            #pragma unroll
            for (int k = 0; k < 4; ++k)
                *(short8v*)&Xs[(base + ci0 + k * 8) ^ sw] = *(const short8v*)&src[k * 8];
        } else {
            short8v z = {};
            #pragma unroll
            for (int k = 0; k < 4; ++k)
                *(short8v*)&Xs[(base + ci0 + k * 8) ^ sw] = z;
        }
    }
    __syncthreads();

    int yl = w >> 1, xb = (w & 1) * 16;
    f32x4 acc[4] = {};
    #pragma unroll
    for (int ky = 0; ky < 3; ++ky)
        #pragma unroll
        for (int kx = 0; kx < 3; ++kx) {
            int tap = ky * 3 + kx;
            #pragma unroll
            for (int kh = 0; kh < 2; ++kh) {
                int xa = xb + lr + kx;
                int e = (((yl + ky) * 34 + xa) << 6) + kh * 32 + g * 8;
                short8v af = *(const short8v*)&Xs[e ^ ((xa & 7) << 3)];
                int fb = (tap * 2 + kh) * 4 * 512 + lr * 32 + g * 8;
                #pragma unroll
                for (int nf = 0; nf < 4; ++nf) {
                    short8v bf_ = *(const short8v*)&Wcv2[fb + nf * 512];
                    acc[nf] = __builtin_amdgcn_mfma_f32_16x16x32_bf16(af, bf_, acc[nf], 0, 0, 0);
                }
            }
        }

    #pragma unroll
    for (int nf = 0; nf < 4; ++nf) {
        int co = nf * 16 + lr;
        float bias = cb[co];
        int h = co >> 5, d = co & 31;
        unsigned int u01 = cvtpk_bf16(acc[nf][0] + bias, acc[nf][1] + bias);
        unsigned int u23 = cvtpk_bf16(acc[nf][2] + bias, acc[nf][3] + bias);
        ushort_t sv[4] = {(ushort_t)(u01 & 0xFFFFu), (ushort_t)(u01 >> 16),
                          (ushort_t)(u23 & 0xFFFFu), (ushort_t)(u23 >> 16)};
        #pragma unroll
        for (int r = 0; r < 4; ++r) {
            int px = w * 16 + g * 4 + r;
            int n = y0 * 32 + px;
            Kbf[(((size_t)(b * 8 + h) << 10) | n) * 32 + d] = sv[r];
        }
    }
}

// ---------------------------------------------------------------------------
// Kernel 4: MFMA flash attention, split=1, double-buffered K/V (1 barrier/tile),
// swapped QK^T, no-max exp2 softmax, direct normalized bf16 output.
// grid (16 qtiles, 32 bh), 4 waves x 16 q rows. cvt_pk softmax conversions.
// ---------------------------------------------------------------------------
__global__ __launch_bounds__(256) void attn_mfma4(
    const ushort_t* __restrict__ Qbf, const ushort_t* __restrict__ Kbf,
    const ushort_t* __restrict__ VTbf, ushort_t* __restrict__ AObf)
{
    __shared__ ushort_t Kt[2][64][32];
    __shared__ ushort_t VT[2][32][72];
    __shared__ ushort_t Ps[4][16][72];

    int bh = blockIdx.y, q0 = blockIdx.x * 64;
    int tid = threadIdx.x, w = tid >> 6, l = tid & 63, lr = l & 15, g = l >> 4;
    int vd = tid >> 3, vn = (tid & 7) * 8;

    short8v qfrag = *(const short8v*)&Qbf[((size_t)bh * 1024 + q0 + w * 16 + lr) * 32 + g * 8];

    f32x4 accO[2] = {};
    float lsum = 0.f;
    const f32x4 zero = {};

    // prologue: stage tile 0 into buf 0
    ((short8v*)&Kt[0][0][0])[tid] =
        *(const short8v*)&Kbf[((size_t)bh * 1024) * 32 + tid * 8];
    *(short8v*)&VT[0][vd][vn] =
        *(const short8v*)&VTbf[((size_t)bh * 32 + vd) * 1024 + vn];

    for (int mt = 0; mt < 16; ++mt) {
        int cur = mt & 1, nb = cur ^ 1;
        __syncthreads();   // staged buf[cur] visible; prev reads of buf[nb] done

        short8v kreg, vreg;
        bool hasNext = (mt + 1) < 16;
        if (hasNext) {
            int m1 = (mt + 1) * 64;
            kreg = *(const short8v*)&Kbf[((size_t)bh * 1024 + m1) * 32 + tid * 8];
            vreg = *(const short8v*)&VTbf[((size_t)bh * 32 + vd) * 1024 + m1 + vn];
        }

        // swapped QK^T: lane holds q=lr, kpos = 16t + 4g + r
        f32x4 st[4];
        #pragma unroll
        for (int t = 0; t < 4; ++t) {
            short8v kf = *(const short8v*)&Kt[cur][t * 16 + lr][g * 8];
            st[t] = __builtin_amdgcn_mfma_f32_16x16x32_bf16(kf, qfrag, zero, 0, 0, 0);
        }

        // exp2 (no max), deferred l, HW-paired bf16 pack, b64 P write
        #pragma unroll
        for (int t = 0; t < 4; ++t) {
            float p0 = exp2f(st[t][0]), p1 = exp2f(st[t][1]);
            float p2 = exp2f(st[t][2]), p3 = exp2f(st[t][3]);
            lsum += (p0 + p1) + (p2 + p3);
            uint2 pw;
            pw.x = cvtpk_bf16(p0, p1);
            pw.y = cvtpk_bf16(p2, p3);
            *(uint2*)&Ps[w][lr][t * 16 + g * 4] = pw;
        }

        // PV: O(16x32) += P(16x64) @ V(64x32)
        #pragma unroll
        for (int kt = 0; kt < 2; ++kt) {
            short8v pa = *(const short8v*)&Ps[w][lr][kt * 32 + g * 8];
            #pragma unroll
            for (int nt = 0; nt < 2; ++nt) {
                short8v vb = *(const short8v*)&VT[cur][nt * 16 + lr][kt * 32 + g * 8];
                accO[nt] = __builtin_amdgcn_mfma_f32_16x16x32_bf16(pa, vb, accO[nt], 0, 0, 0);
            }
        }

        if (hasNext) {
            ((short8v*)&Kt[nb][0][0])[tid] = kreg;
            *(short8v*)&VT[nb][vd][vn] = vreg;
        }
    }

    lsum += __shfl_xor(lsum, 16);
    lsum += __shfl_xor(lsum, 32);

    int b = bh >> 3, h = bh & 7;
    #pragma unroll
    for (int r = 0; r < 4; ++r) {
        float lv = __uint_as_float((unsigned)__builtin_amdgcn_ds_bpermute(
            (g * 4 + r) * 4, (int)__float_as_uint(lsum)));
        float inv = 1.0f / lv;
        int n = q0 + w * 16 + g * 4 + r;
        unsigned int u = cvtpk_bf16(accO[0][r] * inv, accO[1][r] * inv);
        AObf[((size_t)(b * 1024 + n)) * 256 + h * 32 + lr]      = (ushort_t)(u & 0xFFFFu);
        AObf[((size_t)(b * 1024 + n)) * 256 + h * 32 + 16 + lr] = (ushort_t)(u >> 16);
    }
}

// ---------------------------------------------------------------------------
// Kernel 5: output GEMM  out = AObf @ Wo + bo (fp32 out). grid (4,64).
// ---------------------------------------------------------------------------
__global__ __launch_bounds__(256) void out_gemm(
    const ushort_t* __restrict__ A, const ushort_t* __restrict__ WoT,
    const float* __restrict__ bo, float* __restrict__ out)
{
    __shared__ ushort_t As[64][136];
    __shared__ ushort_t Bs[64][136];
    int colBase = blockIdx.x * 64, rowBase = blockIdx.y * 64;
    int tid = threadIdx.x;
    int w = tid >> 6, l = tid & 63, lr = l & 15, g = l >> 4;
    int wr = w >> 1, wc = w & 1;
    int tr = tid >> 2, tq = tid & 3;
    f32x4 acc[2][2] = {};

    for (int kb = 0; kb < 256; kb += 128) {
        #pragma unroll
        for (int i = 0; i < 4; ++i)
            *(short8v*)&As[tr][tq * 32 + i * 8] =
                *(const short8v*)&A[(size_t)(rowBase + tr) * 256 + kb + tq * 32 + i * 8];
        #pragma unroll
        for (int i = 0; i < 4; ++i)
            *(short8v*)&Bs[tr][tq * 32 + i * 8] =
                *(const short8v*)&WoT[(size_t)(colBase + tr) * 256 + kb + tq * 32 + i * 8];
        __syncthreads();
        #pragma unroll
        for (int ks = 0; ks < 4; ++ks) {
            short8v a0 = *(const short8v*)&As[wr * 32 + lr][ks * 32 + g * 8];
            short8v a1 = *(const short8v*)&As[wr * 32 + 16 + lr][ks * 32 + g * 8];
            short8v b0 = *(const short8v*)&Bs[wc * 32 + lr][ks * 32 + g * 8];
            short8v b1 = *(const short8v*)&Bs[wc * 32 + 16 + lr][ks * 32 + g * 8];
            acc[0][0] = __builtin_amdgcn_mfma_f32_16x16x32_bf16(a0, b0, acc[0][0], 0, 0, 0);
            acc[0][1] = __builtin_amdgcn_mfma_f32_16x16x32_bf16(a0, b1, acc[0][1], 0, 0, 0);
            acc[1][0] = __builtin_amdgcn_mfma_f32_16x16x32_bf16(a1, b0, acc[1][0], 0, 0, 0);
            acc[1][1] = __builtin_amdgcn_mfma_f32_16x16x32_bf16(a1, b1, acc[1][1], 0, 0, 0);
        }
        __syncthreads();
    }

    #pragma unroll
    for (int fr = 0; fr < 2; ++fr)
        #pragma unroll
        for (int fc = 0; fc < 2; ++fc) {
            int c = colBase + wc * 32 + fc * 16 + lr;
            float bv = bo[c];
            int nb = rowBase + wr * 32 + fr * 16 + g * 4;
            #pragma unroll
            for (int r = 0; r < 4; ++r)
                out[(size_t)(nb + r) * 256 + c] = acc[fr][fc][r] + bv;
        }
}

// ---------------------------------------------------------------------------
extern "C" void kernel_launch(void* const* d_in, const int* in_sizes, int n_in,
                              void* d_out, int out_size, void* d_ws, size_t ws_size,
                              hipStream_t stream)
{
    const float* src1 = (const float*)d_in[0];
    const float* src2 = (const float*)d_in[1];
    const float* Wq1  = (const float*)d_in[2];
    const float* bq1  = (const float*)d_in[3];
    const float* Wq2  = (const float*)d_in[4];
    const float* bq2  = (const float*)d_in[5];
    const float* Wk   = (const float*)d_in[6];
    const float* bk   = (const float*)d_in[7];
    const float* Wv   = (const float*)d_in[8];
    const float* bv   = (const float*)d_in[9];
    const float* cw   = (const float*)d_in[10];
    const float* cb   = (const float*)d_in[11];
    const float* Wo   = (const float*)d_in[12];
    const float* bo   = (const float*)d_in[13];
    float* out = (float*)d_out;

    char* base = (char*)d_ws;
    const size_t MB = 1u << 20;
    const size_t KB = 1u << 10;
    ushort_t* X1bf = (ushort_t*)(base + 0 * MB);     // 2 MB
    ushort_t* X2bf = (ushort_t*)(base + 2 * MB);     // 2 MB
    ushort_t* Qbf  = (ushort_t*)(base + 4 * MB);     // 2 MB  [32 bh][1024][32]
    ushort_t* Kbf  = (ushort_t*)(base + 6 * MB);     // 2 MB
    ushort_t* VTbf = (ushort_t*)(base + 8 * MB);     // 2 MB  [32 bh][32][1024]
    ushort_t* AObf = (ushort_t*)(base + 10 * MB);    // 2 MB  [4096][256]
    ushort_t* CVbf = (ushort_t*)(base + 12 * MB);    // 512 KB [4096][64]
    ushort_t* WcatT= (ushort_t*)(base + 12 * MB + 512 * KB);   // 384 KB
    ushort_t* WoT  = (ushort_t*)(base + 12 * MB + 896 * KB);   // 128 KB
    float*    bcat = (float*)(base + 13 * MB);                 // 3 KB
    ushort_t* Wcv2 = (ushort_t*)(base + 13 * MB + 4 * KB);     // 72 KB

    pe_prep_kernel<<<1097, 256, 0, stream>>>(
        src1, src2, Wq1, Wq2, Wk, Wv, Wo, cw, bq1, bq2, bk, bv,
        X1bf, X2bf, WcatT, WoT, bcat, Wcv2);
    proj_gemm<<<dim3(12, 64), 256, 0, stream>>>(
        X1bf, X2bf, WcatT, bcat, Qbf, Kbf, VTbf, CVbf);
    conv_mfma<<<64, 256, 0, stream>>>(CVbf, Wcv2, cb, Kbf);
    attn_mfma4<<<dim3(16, 32), 256, 0, stream>>>(Qbf, Kbf, VTbf, AObf);
    out_gemm<<<dim3(4, 64), 256, 0, stream>>>(AObf, WoT, bo, out);
}

// Round 12
// 45.920 us; speedup vs baseline: 12.2276x; 1.0403x over previous
//
#include <hip/hip_runtime.h>
#include <cstdint>
#include <cstddef>

typedef __attribute__((ext_vector_type(8))) short short8v;   // 8 bf16 = 4 VGPRs
typedef __attribute__((ext_vector_type(4))) short short4v;   // 4 bf16 = 8B
typedef __attribute__((ext_vector_type(4))) float f32x4;
typedef unsigned short ushort_t;

__device__ inline unsigned short f2bf(float x) {
    unsigned int u = __float_as_uint(x);
    return (unsigned short)((u + 0x7FFFu + ((u >> 16) & 1u)) >> 16);   // RNE
}

// HW paired conversion: lo -> bits[15:0], hi -> bits[31:16], RNE (gfx950)
__device__ inline unsigned int cvtpk_bf16(float lo, float hi) {
    unsigned int r;
    asm("v_cvt_pk_bf16_f32 %0, %1, %2" : "=v"(r) : "v"(lo), "v"(hi));
    return r;
}

// ---------------------------------------------------------------------------
// Kernel 1 (fused): blocks [0,512):   X1/X2 = bf16(src + pe), vectorized
//                   blocks [512,576): QKVO weight transpose/fold prep
//                   blocks [576,585): conv weight pack (per tap)
// ---------------------------------------------------------------------------
__global__ __launch_bounds__(256) void pe_prep_kernel(
    const float* __restrict__ src1, const float* __restrict__ src2,
    const float* __restrict__ Wq1, const float* __restrict__ Wq2,
    const float* __restrict__ Wk, const float* __restrict__ Wv,
    const float* __restrict__ Wo, const float* __restrict__ cw,
    const float* __restrict__ bq1, const float* __restrict__ bq2,
    const float* __restrict__ bk, const float* __restrict__ bv,
    ushort_t* __restrict__ X1, ushort_t* __restrict__ X2,
    ushort_t* __restrict__ WcatT, ushort_t* __restrict__ WoT,
    float* __restrict__ bcat, ushort_t* __restrict__ Wcv2)
{
    __shared__ ushort_t Ts[64][72];
    int bx = blockIdx.x;
    int t = threadIdx.x;

    if (bx < 512) {
        // ---- PE add, 2 channels/thread, float2 loads, packed 4B stores ----
        int n = bx * 2 + (t >> 7);          // 2 n's per block
        int cp = (t & 127) * 2;             // even channel pair (same side of 128)
        int row = n >> 5, col = n & 31;
        float pos = (cp < 128) ? (float)(row + 1) : (float)(col + 1);
        float f0 = expf(-0.14391156831212787f * (float)(cp & 63));
        float f1 = expf(-0.14391156831212787f * (float)((cp + 1) & 63));
        float pe0 = sinf(pos * f0);
        float pe1 = sinf(pos * f1);
        #pragma unroll
        for (int b = 0; b < 4; ++b) {
            size_t idx = ((size_t)b * 1024 + n) * 256 + cp;
            float2 s1 = *(const float2*)&src1[idx];
            float2 s2 = *(const float2*)&src2[idx];
            *(unsigned int*)&X1[idx] = cvtpk_bf16(s1.x + pe0, s1.y + pe1);
            *(unsigned int*)&X2[idx] = cvtpk_bf16(s2.x + pe0, s2.y + pe1);
        }
        return;
    }

    if (bx < 576) {
        int idx = bx - 512;
        int kt = idx & 3, ct = idx >> 2;
        int k0 = kt * 64;
        const float* W; int csrc; int fold = 0; ushort_t* dst; int dstbase;
        if (ct < 2)       { W = Wq1; csrc = ct * 64;        fold = 1; dst = WcatT; dstbase = ct * 64; }
        else if (ct < 4)  { W = Wq2; csrc = (ct - 2) * 64;  fold = 1; dst = WcatT; dstbase = ct * 64; }
        else if (ct < 8)  { W = Wk;  csrc = (ct - 4) * 64;            dst = WcatT; dstbase = ct * 64; }
        else if (ct < 12) { W = Wv;  csrc = (ct - 8) * 64;            dst = WcatT; dstbase = ct * 64; }
        else              { W = Wo;  csrc = (ct - 12) * 64;           dst = WoT;   dstbase = (ct - 12) * 64; }
        if (kt == 0) {
            if (ct == 0 && t < 128) bcat[t] = bq1[t] + bq1[t + 128];
            if (ct == 2 && t < 128) bcat[128 + t] = bq2[t] + bq2[t + 128];
            if (ct == 4) bcat[256 + t] = bk[t];
            if (ct == 8) bcat[512 + t] = bv[t];
        }

        int kr = t >> 2, cq = t & 3;
        #pragma unroll
        for (int i = 0; i < 4; ++i) {
            int cc = cq * 16 + i * 4;
            float4 v = *(const float4*)&W[(size_t)(k0 + kr) * 256 + csrc + cc];
            if (fold) {
                float4 v2 = *(const float4*)&W[(size_t)(k0 + kr) * 256 + csrc + cc + 128];
                v.x += v2.x; v.y += v2.y; v.z += v2.z; v.w += v2.w;
            }
            unsigned int u01 = cvtpk_bf16(v.x, v.y);
            unsigned int u23 = cvtpk_bf16(v.z, v.w);
            Ts[kr][cc + 0] = (ushort_t)(u01 & 0xFFFFu); Ts[kr][cc + 1] = (ushort_t)(u01 >> 16);
            Ts[kr][cc + 2] = (ushort_t)(u23 & 0xFFFFu); Ts[kr][cc + 3] = (ushort_t)(u23 >> 16);
        }
        __syncthreads();
        int cr = t >> 2, kq = t & 3;
        ushort_t tmp[16];
        #pragma unroll
        for (int i = 0; i < 16; ++i) tmp[i] = Ts[kq * 16 + i][cr];
        *(short8v*)&dst[(size_t)(dstbase + cr) * 256 + k0 + kq * 16]     = *(short8v*)&tmp[0];
        *(short8v*)&dst[(size_t)(dstbase + cr) * 256 + k0 + kq * 16 + 8] = *(short8v*)&tmp[8];
        return;
    }

    {
        int tap = bx - 576;
        int ci = t >> 2, co0 = (t & 3) * 16;
        #pragma unroll
        for (int i = 0; i < 16; ++i)
            Ts[ci][co0 + i] = f2bf(cw[((size_t)(tap * 64 + ci)) * 64 + co0 + i]);
        __syncthreads();
        int co = t >> 2, ci0 = (t & 3) * 16;
        ushort_t tmp[16];
        #pragma unroll
        for (int i = 0; i < 16; ++i) tmp[i] = Ts[ci0 + i][co];
        int kh = ci0 >> 5;
        int f = (tap * 2 + kh) * 4 + (co >> 4);
        int off = f * 512 + (co & 15) * 32 + (ci0 & 31);
        *(short8v*)&Wcv2[off]     = *(short8v*)&tmp[0];
        *(short8v*)&Wcv2[off + 8] = *(short8v*)&tmp[8];
    }
}

// ---------------------------------------------------------------------------
// Kernel 2: merged projection GEMM. grid (12, 64); 64x64 tile, BK=128, 4 waves.
// ---------------------------------------------------------------------------
__global__ __launch_bounds__(256) void proj_gemm(
    const ushort_t* __restrict__ X1, const ushort_t* __restrict__ X2,
    const ushort_t* __restrict__ WcatT, const float* __restrict__ bcat,
    ushort_t* __restrict__ Qbf, ushort_t* __restrict__ Kbf,
    ushort_t* __restrict__ VTbf, ushort_t* __restrict__ CVbf)
{
    __shared__ ushort_t As[64][136];
    __shared__ ushort_t Bs[64][136];
    int colBase = blockIdx.x * 64, rowBase = blockIdx.y * 64;
    const ushort_t* A = (colBase >= 128 && colBase < 256) ? X2 : X1;
    int tid = threadIdx.x;
    int w = tid >> 6, l = tid & 63, lr = l & 15, g = l >> 4;
    int wr = w >> 1, wc = w & 1;
    int tr = tid >> 2, tq = tid & 3;
    f32x4 acc[2][2] = {};

    for (int kb = 0; kb < 256; kb += 128) {
        #pragma unroll
        for (int i = 0; i < 4; ++i)
            *(short8v*)&As[tr][tq * 32 + i * 8] =
                *(const short8v*)&A[(size_t)(rowBase + tr) * 256 + kb + tq * 32 + i * 8];
        #pragma unroll
        for (int i = 0; i < 4; ++i)
            *(short8v*)&Bs[tr][tq * 32 + i * 8] =
                *(const short8v*)&WcatT[(size_t)(colBase + tr) * 256 + kb + tq * 32 + i * 8];
        __syncthreads();
        #pragma unroll
        for (int ks = 0; ks < 4; ++ks) {
            short8v a0 = *(const short8v*)&As[wr * 32 + lr][ks * 32 + g * 8];
            short8v a1 = *(const short8v*)&As[wr * 32 + 16 + lr][ks * 32 + g * 8];
            short8v b0 = *(const short8v*)&Bs[wc * 32 + lr][ks * 32 + g * 8];
            short8v b1 = *(const short8v*)&Bs[wc * 32 + 16 + lr][ks * 32 + g * 8];
            acc[0][0] = __builtin_amdgcn_mfma_f32_16x16x32_bf16(a0, b0, acc[0][0], 0, 0, 0);
            acc[0][1] = __builtin_amdgcn_mfma_f32_16x16x32_bf16(a0, b1, acc[0][1], 0, 0, 0);
            acc[1][0] = __builtin_amdgcn_mfma_f32_16x16x32_bf16(a1, b0, acc[1][0], 0, 0, 0);
            acc[1][1] = __builtin_amdgcn_mfma_f32_16x16x32_bf16(a1, b1, acc[1][1], 0, 0, 0);
        }
        __syncthreads();
    }

    const float scale = 0.25503532182457352f;   // log2(e)/sqrt(32)
    #pragma unroll
    for (int fr = 0; fr < 2; ++fr)
        #pragma unroll
        for (int fc = 0; fc < 2; ++fc) {
            int c = colBase + wc * 32 + fc * 16 + lr;
            float bv = bcat[c];
            int nb = rowBase + wr * 32 + fr * 16 + g * 4;
            int b = nb >> 10;
            float vv[4];
            #pragma unroll
            for (int r = 0; r < 4; ++r) vv[r] = acc[fr][fc][r] + bv;
            if (c < 256) {
                #pragma unroll
                for (int r = 0; r < 4; ++r) vv[r] *= scale;
            }
            unsigned int u01 = cvtpk_bf16(vv[0], vv[1]);
            unsigned int u23 = cvtpk_bf16(vv[2], vv[3]);
            ushort_t sv[4] = {(ushort_t)(u01 & 0xFFFFu), (ushort_t)(u01 >> 16),
                              (ushort_t)(u23 & 0xFFFFu), (ushort_t)(u23 >> 16)};
            if (c < 512) {
                #pragma unroll
                for (int r = 0; r < 4; ++r) {
                    int n = nb + r;
                    if (c < 128) {
                        int h = 4 + (c >> 5), d = c & 31;
                        Qbf[(((size_t)(b * 8 + h) << 10) | (n & 1023)) * 32 + d] = sv[r];
                    } else if (c < 256) {
                        int c2 = c - 128;
                        int h = c2 >> 5, d = c2 & 31;
                        Qbf[(((size_t)(b * 8 + h) << 10) | (n & 1023)) * 32 + d] = sv[r];
                    } else {
                        int c3 = c - 256;
                        if (c3 < 128) {
                            int h = 4 + (c3 >> 5), d = c3 & 31;
                            Kbf[(((size_t)(b * 8 + h) << 10) | (n & 1023)) * 32 + d] = sv[r];
                        } else if (c3 < 192) {
                            CVbf[(size_t)n * 64 + (c3 - 128)] = sv[r];
                        } else {
                            int h = 2 + ((c3 - 192) >> 5), d = c3 & 31;
                            Kbf[(((size_t)(b * 8 + h) << 10) | (n & 1023)) * 32 + d] = sv[r];
                        }
                    }
                }
            } else {
                int c4 = c - 512;
                int h = c4 >> 5, d = c4 & 31;
                uint2 pk;
                pk.x = u01; pk.y = u23;
                *(uint2*)&VTbf[((size_t)((b * 8 + h) * 32 + d)) * 1024 + (nb & 1023)] = pk;
            }
        }
}

// ---------------------------------------------------------------------------
// Kernel 3: 3x3 SAME conv as MFMA implicit GEMM.
// 128 blocks = (b, y-pair, co-half); 4 waves x 16 px, 36 MFMA each.
// ---------------------------------------------------------------------------
__global__ __launch_bounds__(256) void conv_mfma(
    const ushort_t* __restrict__ CVbf, const ushort_t* __restrict__ Wcv2,
    const float* __restrict__ cb, ushort_t* __restrict__ Kbf)
{
    __shared__ ushort_t Xs[8704];          // 4*34*64
    int blk = blockIdx.x;
    int b = blk >> 5, rem = blk & 31;
    int y0 = (rem >> 1) * 2, chalf = rem & 1;
    int tid = threadIdx.x, w = tid >> 6, l = tid & 63, lr = l & 15, g = l >> 4;

    for (int p = tid >> 1; p < 136; p += 128) {
        int ry = p / 34, xc = p % 34;
        int ci0 = (tid & 1) * 32;
        int gy = y0 - 1 + ry, gx = xc - 1;
        int base = p << 6;
        int sw = (xc & 7) << 3;
        if ((unsigned)gy < 32u && (unsigned)gx < 32u) {
            const ushort_t* src = &CVbf[((size_t)(b * 1024 + gy * 32 + gx)) * 64 + ci0];
            #pragma unroll
            for (int k = 0; k < 4; ++k)
                *(short8v*)&Xs[(base + ci0 + k * 8) ^ sw] = *(const short8v*)&src[k * 8];
        } else {
            short8v z = {};
            #pragma unroll
            for (int k = 0; k < 4; ++k)
                *(short8v*)&Xs[(base + ci0 + k * 8) ^ sw] = z;
        }
    }
    __syncthreads();

    int yl = w >> 1, xb = (w & 1) * 16;
    f32x4 acc[2] = {};
    #pragma unroll
    for (int ky = 0; ky < 3; ++ky)
        #pragma unroll
        for (int kx = 0; kx < 3; ++kx) {
            int tap = ky * 3 + kx;
            #pragma unroll
            for (int kh = 0; kh < 2; ++kh) {
                int xa = xb + lr + kx;
                int e = (((yl + ky) * 34 + xa) << 6) + kh * 32 + g * 8;
                short8v af = *(const short8v*)&Xs[e ^ ((xa & 7) << 3)];
                int fb = ((tap * 2 + kh) * 4 + chalf * 2) * 512 + lr * 32 + g * 8;
                #pragma unroll
                for (int nf = 0; nf < 2; ++nf) {
                    short8v bf_ = *(const short8v*)&Wcv2[fb + nf * 512];
                    acc[nf] = __builtin_amdgcn_mfma_f32_16x16x32_bf16(af, bf_, acc[nf], 0, 0, 0);
                }
            }
        }

    #pragma unroll
    for (int nf = 0; nf < 2; ++nf) {
        int co = chalf * 32 + nf * 16 + lr;
        float bias = cb[co];
        int h = chalf, d = nf * 16 + lr;
        unsigned int u01 = cvtpk_bf16(acc[nf][0] + bias, acc[nf][1] + bias);
        unsigned int u23 = cvtpk_bf16(acc[nf][2] + bias, acc[nf][3] + bias);
        ushort_t sv[4] = {(ushort_t)(u01 & 0xFFFFu), (ushort_t)(u01 >> 16),
                          (ushort_t)(u23 & 0xFFFFu), (ushort_t)(u23 >> 16)};
        #pragma unroll
        for (int r = 0; r < 4; ++r) {
            int px = w * 16 + g * 4 + r;
            int n = y0 * 32 + px;
            Kbf[(((size_t)(b * 8 + h) << 10) | n) * 32 + d] = sv[r];
        }
    }
}

// ---------------------------------------------------------------------------
// Kernel 4: MFMA flash attention, split=1, double-buffered K/V (1 barrier/tile),
// swapped QK^T, no-max exp2 softmax, direct normalized bf16 output.
// grid (16 qtiles, 32 bh), 4 waves x 16 q rows. cvt_pk softmax conversions.
// ---------------------------------------------------------------------------
__global__ __launch_bounds__(256) void attn_mfma4(
    const ushort_t* __restrict__ Qbf, const ushort_t* __restrict__ Kbf,
    const ushort_t* __restrict__ VTbf, ushort_t* __restrict__ AObf)
{
    __shared__ ushort_t Kt[2][64][32];
    __shared__ ushort_t VT[2][32][72];
    __shared__ ushort_t Ps[4][16][72];

    int bh = blockIdx.y, q0 = blockIdx.x * 64;
    int tid = threadIdx.x, w = tid >> 6, l = tid & 63, lr = l & 15, g = l >> 4;
    int vd = tid >> 3, vn = (tid & 7) * 8;

    short8v qfrag = *(const short8v*)&Qbf[((size_t)bh * 1024 + q0 + w * 16 + lr) * 32 + g * 8];

    f32x4 accO[2] = {};
    float lsum = 0.f;
    const f32x4 zero = {};

    // prologue: stage tile 0 into buf 0
    ((short8v*)&Kt[0][0][0])[tid] =
        *(const short8v*)&Kbf[((size_t)bh * 1024) * 32 + tid * 8];
    *(short8v*)&VT[0][vd][vn] =
        *(const short8v*)&VTbf[((size_t)bh * 32 + vd) * 1024 + vn];

    for (int mt = 0; mt < 16; ++mt) {
        int cur = mt & 1, nb = cur ^ 1;
        __syncthreads();   // staged buf[cur] visible; prev reads of buf[nb] done

        short8v kreg, vreg;
        bool hasNext = (mt + 1) < 16;
        if (hasNext) {
            int m1 = (mt + 1) * 64;
            kreg = *(const short8v*)&Kbf[((size_t)bh * 1024 + m1) * 32 + tid * 8];
            vreg = *(const short8v*)&VTbf[((size_t)bh * 32 + vd) * 1024 + m1 + vn];
        }

        // swapped QK^T: lane holds q=lr, kpos = 16t + 4g + r
        f32x4 st[4];
        #pragma unroll
        for (int t = 0; t < 4; ++t) {
            short8v kf = *(const short8v*)&Kt[cur][t * 16 + lr][g * 8];
            st[t] = __builtin_amdgcn_mfma_f32_16x16x32_bf16(kf, qfrag, zero, 0, 0, 0);
        }

        // exp2 (no max), deferred l, HW-paired bf16 pack, b64 P write
        #pragma unroll
        for (int t = 0; t < 4; ++t) {
            float p0 = exp2f(st[t][0]), p1 = exp2f(st[t][1]);
            float p2 = exp2f(st[t][2]), p3 = exp2f(st[t][3]);
            lsum += (p0 + p1) + (p2 + p3);
            uint2 pw;
            pw.x = cvtpk_bf16(p0, p1);
            pw.y = cvtpk_bf16(p2, p3);
            *(uint2*)&Ps[w][lr][t * 16 + g * 4] = pw;
        }

        // PV: O(16x32) += P(16x64) @ V(64x32)
        #pragma unroll
        for (int kt = 0; kt < 2; ++kt) {
            short8v pa = *(const short8v*)&Ps[w][lr][kt * 32 + g * 8];
            #pragma unroll
            for (int nt = 0; nt < 2; ++nt) {
                short8v vb = *(const short8v*)&VT[cur][nt * 16 + lr][kt * 32 + g * 8];
                accO[nt] = __builtin_amdgcn_mfma_f32_16x16x32_bf16(pa, vb, accO[nt], 0, 0, 0);
            }
        }

        if (hasNext) {
            ((short8v*)&Kt[nb][0][0])[tid] = kreg;
            *(short8v*)&VT[nb][vd][vn] = vreg;
        }
    }

    lsum += __shfl_xor(lsum, 16);
    lsum += __shfl_xor(lsum, 32);

    int b = bh >> 3, h = bh & 7;
    #pragma unroll
    for (int r = 0; r < 4; ++r) {
        float lv = __uint_as_float((unsigned)__builtin_amdgcn_ds_bpermute(
            (g * 4 + r) * 4, (int)__float_as_uint(lsum)));
        float inv = 1.0f / lv;
        int n = q0 + w * 16 + g * 4 + r;
        unsigned int u = cvtpk_bf16(accO[0][r] * inv, accO[1][r] * inv);
        AObf[((size_t)(b * 1024 + n)) * 256 + h * 32 + lr]      = (ushort_t)(u & 0xFFFFu);
        AObf[((size_t)(b * 1024 + n)) * 256 + h * 32 + 16 + lr] = (ushort_t)(u >> 16);
    }
}

// ---------------------------------------------------------------------------
// Kernel 5: output GEMM  out = AObf @ Wo + bo (fp32 out). grid (4,64).
// ---------------------------------------------------------------------------
__global__ __launch_bounds__(256) void out_gemm(
    const ushort_t* __restrict__ A, const ushort_t* __restrict__ WoT,
    const float* __restrict__ bo, float* __restrict__ out)
{
    __shared__ ushort_t As[64][136];
    __shared__ ushort_t Bs[64][136];
    int colBase = blockIdx.x * 64, rowBase = blockIdx.y * 64;
    int tid = threadIdx.x;
    int w = tid >> 6, l = tid & 63, lr = l & 15, g = l >> 4;
    int wr = w >> 1, wc = w & 1;
    int tr = tid >> 2, tq = tid & 3;
    f32x4 acc[2][2] = {};

    for (int kb = 0; kb < 256; kb += 128) {
        #pragma unroll
        for (int i = 0; i < 4; ++i)
            *(short8v*)&As[tr][tq * 32 + i * 8] =
                *(const short8v*)&A[(size_t)(rowBase + tr) * 256 + kb + tq * 32 + i * 8];
        #pragma unroll
        for (int i = 0; i < 4; ++i)
            *(short8v*)&Bs[tr][tq * 32 + i * 8] =
                *(const short8v*)&WoT[(size_t)(colBase + tr) * 256 + kb + tq * 32 + i * 8];
        __syncthreads();
        #pragma unroll
        for (int ks = 0; ks < 4; ++ks) {
            short8v a0 = *(const short8v*)&As[wr * 32 + lr][ks * 32 + g * 8];
            short8v a1 = *(const short8v*)&As[wr * 32 + 16 + lr][ks * 32 + g * 8];
            short8v b0 = *(const short8v*)&Bs[wc * 32 + lr][ks * 32 + g * 8];
            short8v b1 = *(const short8v*)&Bs[wc * 32 + 16 + lr][ks * 32 + g * 8];
            acc[0][0] = __builtin_amdgcn_mfma_f32_16x16x32_bf16(a0, b0, acc[0][0], 0, 0, 0);
            acc[0][1] = __builtin_amdgcn_mfma_f32_16x16x32_bf16(a0, b1, acc[0][1], 0, 0, 0);
            acc[1][0] = __builtin_amdgcn_mfma_f32_16x16x32_bf16(a1, b0, acc[1][0], 0, 0, 0);
            acc[1][1] = __builtin_amdgcn_mfma_f32_16x16x32_bf16(a1, b1, acc[1][1], 0, 0, 0);
        }
        __syncthreads();
    }

    #pragma unroll
    for (int fr = 0; fr < 2; ++fr)
        #pragma unroll
        for (int fc = 0; fc < 2; ++fc) {
            int c = colBase + wc * 32 + fc * 16 + lr;
            float bv = bo[c];
            int nb = rowBase + wr * 32 + fr * 16 + g * 4;
            #pragma unroll
            for (int r = 0; r < 4; ++r)
                out[(size_t)(nb + r) * 256 + c] = acc[fr][fc][r] + bv;
        }
}

// ---------------------------------------------------------------------------
extern "C" void kernel_launch(void* const* d_in, const int* in_sizes, int n_in,
                              void* d_out, int out_size, void* d_ws, size_t ws_size,
                              hipStream_t stream)
{
    const float* src1 = (const float*)d_in[0];
    const float* src2 = (const float*)d_in[1];
    const float* Wq1  = (const float*)d_in[2];
    const float* bq1  = (const float*)d_in[3];
    const float* Wq2  = (const float*)d_in[4];
    const float* bq2  = (const float*)d_in[5];
    const float* Wk   = (const float*)d_in[6];
    const float* bk   = (const float*)d_in[7];
    const float* Wv   = (const float*)d_in[8];
    const float* bv   = (const float*)d_in[9];
    const float* cw   = (const float*)d_in[10];
    const float* cb   = (const float*)d_in[11];
    const float* Wo   = (const float*)d_in[12];
    const float* bo   = (const float*)d_in[13];
    float* out = (float*)d_out;

    char* base = (char*)d_ws;
    const size_t MB = 1u << 20;
    const size_t KB = 1u << 10;
    ushort_t* X1bf = (ushort_t*)(base + 0 * MB);     // 2 MB
    ushort_t* X2bf = (ushort_t*)(base + 2 * MB);     // 2 MB
    ushort_t* Qbf  = (ushort_t*)(base + 4 * MB);     // 2 MB  [32 bh][1024][32]
    ushort_t* Kbf  = (ushort_t*)(base + 6 * MB);     // 2 MB
    ushort_t* VTbf = (ushort_t*)(base + 8 * MB);     // 2 MB  [32 bh][32][1024]
    ushort_t* AObf = (ushort_t*)(base + 10 * MB);    // 2 MB  [4096][256]
    ushort_t* CVbf = (ushort_t*)(base + 12 * MB);    // 512 KB [4096][64]
    ushort_t* WcatT= (ushort_t*)(base + 12 * MB + 512 * KB);   // 384 KB
    ushort_t* WoT  = (ushort_t*)(base + 12 * MB + 896 * KB);   // 128 KB
    float*    bcat = (float*)(base + 13 * MB);                 // 3 KB
    ushort_t* Wcv2 = (ushort_t*)(base + 13 * MB + 4 * KB);     // 72 KB

    pe_prep_kernel<<<585, 256, 0, stream>>>(
        src1, src2, Wq1, Wq2, Wk, Wv, Wo, cw, bq1, bq2, bk, bv,
        X1bf, X2bf, WcatT, WoT, bcat, Wcv2);
    proj_gemm<<<dim3(12, 64), 256, 0, stream>>>(
        X1bf, X2bf, WcatT, bcat, Qbf, Kbf, VTbf, CVbf);
    conv_mfma<<<128, 256, 0, stream>>>(CVbf, Wcv2, cb, Kbf);
    attn_mfma4<<<dim3(16, 32), 256, 0, stream>>>(Qbf, Kbf, VTbf, AObf);
    out_gemm<<<dim3(4, 64), 256, 0, stream>>>(AObf, WoT, bo, out);
}